// Round 3
// baseline (582.945 us; speedup 1.0000x reference)
//
#include <hip/hip_runtime.h>
#include <math.h>

// ---------------------------------------------------------------------------
// Types / helpers
// ---------------------------------------------------------------------------
using u16 = unsigned short;
typedef __attribute__((ext_vector_type(8))) short short8;   // 8 x bf16 (raw bits)
typedef __attribute__((ext_vector_type(4))) float f32x4;
typedef __attribute__((ext_vector_type(16))) float f32x16;
typedef __attribute__((ext_vector_type(4))) u16 u16x4;

#define DEV __device__ __forceinline__

DEV u16 f2bf(float f) {                       // f32 -> bf16, round-nearest-even
    unsigned u = __float_as_uint(f);
    u += 0x7fffu + ((u >> 16) & 1u);
    return (u16)(u >> 16);
}
DEV float bf2f(u16 h) { return __uint_as_float(((unsigned)h) << 16); }

DEV short8 ld16(const u16* p) { return *reinterpret_cast<const short8*>(p); }

DEV float gelu_f(float x) { return 0.5f * x * (1.f + erff(x * 0.70710678118654752f)); }

DEV unsigned pk2(float a, float b) {          // two f32 -> packed bf16x2
    return (unsigned)f2bf(a) | ((unsigned)f2bf(b) << 16);
}

// async global->LDS, 16B per lane, LDS dest = wave-uniform base + lane*16
#define GLL16(gp, lp)                                                          \
    __builtin_amdgcn_global_load_lds(                                          \
        (const __attribute__((address_space(1))) void*)(gp),                   \
        (__attribute__((address_space(3))) void*)(lp), 16, 0, 0)

#define VMC(n) asm volatile("s_waitcnt vmcnt(" #n ")" ::: "memory")

// ---------------------------------------------------------------------------
// fp32 -> bf16 convert (weights)
// ---------------------------------------------------------------------------
__global__ void cvt_f32_bf16(const float* __restrict__ in, u16* __restrict__ out, int n4) {
    int i = blockIdx.x * 256 + threadIdx.x;
    if (i >= n4) return;
    float4 v = reinterpret_cast<const float4*>(in)[i];
    u16x4 o;
    o.x = f2bf(v.x); o.y = f2bf(v.y); o.z = f2bf(v.z); o.w = f2bf(v.w);
    reinterpret_cast<u16x4*>(out)[i] = o;
}

// ---------------------------------------------------------------------------
// LayerNorm (fp32 in) -> bf16 out.  One block per row, 256 threads x 4 floats.
// ---------------------------------------------------------------------------
__global__ __launch_bounds__(256) void ln_bf16(const float* __restrict__ x,
                                               const float* __restrict__ gm,
                                               const float* __restrict__ bt,
                                               u16* __restrict__ out) {
    const int row = blockIdx.x, tid = threadIdx.x;
    const float4 v = reinterpret_cast<const float4*>(x + (long)row * 1024)[tid];
    float s  = v.x + v.y + v.z + v.w;
    float sq = v.x * v.x + v.y * v.y + v.z * v.z + v.w * v.w;
#pragma unroll
    for (int off = 1; off <= 32; off <<= 1) {
        s  += __shfl_xor(s, off);
        sq += __shfl_xor(sq, off);
    }
    __shared__ float ss[4], ssq[4];
    const int wave = tid >> 6, lane = tid & 63;
    if (lane == 0) { ss[wave] = s; ssq[wave] = sq; }
    __syncthreads();
    s  = ss[0] + ss[1] + ss[2] + ss[3];
    sq = ssq[0] + ssq[1] + ssq[2] + ssq[3];
    const float mu   = s * (1.f / 1024.f);
    const float var  = sq * (1.f / 1024.f) - mu * mu;
    const float rstd = rsqrtf(var + 1e-5f);
    const float4 g4 = reinterpret_cast<const float4*>(gm)[tid];
    const float4 b4 = reinterpret_cast<const float4*>(bt)[tid];
    u16x4 o;
    o.x = f2bf((v.x - mu) * rstd * g4.x + b4.x);
    o.y = f2bf((v.y - mu) * rstd * g4.y + b4.y);
    o.z = f2bf((v.z - mu) * rstd * g4.z + b4.z);
    o.w = f2bf((v.w - mu) * rstd * g4.w + b4.w);
    reinterpret_cast<u16x4*>(out + (long)row * 1024)[tid] = o;
}

// ---------------------------------------------------------------------------
// 8-phase 256xBN GEMM (m201-style): C[M,N] = A[M,K] @ B[N,K]^T + bias.
// BM=256, BK=64, 512 threads = 8 waves (2M x 4N), per-wave C = 128 x (BN/4).
// LDS: 2 dbuf x {A,B} x {ks0,ks1} halves; halves are [rows][32] bf16 with
// XOR swizzle gp = g ^ ((row>>1)&3) applied via pre-swizzled global source
// (global_load_lds writes linearly) and swizzled ds_read.
// Phase = (dbuf, ks, m-half): reads 4 A-frags (+NREP B-frags on ks-entry),
// stages one half-tile of a future K-tile, barrier, lgkmcnt(0), 4xNREP MFMA,
// barrier.  vmcnt(6/4) only at phases 4 and 8 (3 half-tiles in flight).
// EPI: 0 = bf16 out, 1 = bf16 gelu out, 2 = fp32 out + residual,
//      3 = scatter into Q [BH,S,64], K [BH,S,64], Vt [BH,64,S]
// ---------------------------------------------------------------------------
template <int BN, int EPI>
__global__ __launch_bounds__(512, 2) void gemm8(
    const u16* __restrict__ A, const u16* __restrict__ B,
    const float* __restrict__ bias, const float* res, float* outf,
    u16* __restrict__ outb, u16* __restrict__ Qb, u16* __restrict__ Kb,
    u16* __restrict__ Vtb, int M, int N, int K) {
    constexpr int NREP   = BN / 64;    // B n-frags per wave (4 or 2)
    constexpr int BLOADS = BN / 128;   // gload_lds instrs per wave per B-half

    __shared__ u16 lA[2][2][8192];       // [dbuf][ks][256 rows x 32]
    __shared__ u16 lB[2][2][BN * 32];    // [dbuf][ks][BN rows x 32]

    const int tid = threadIdx.x;
    const int w = tid >> 6, lane = tid & 63;
    const int lo = lane & 15, g = lane >> 4;
    const int wr = w >> 2, wc = w & 3;

    // bijective XCD swizzle (all grids here are multiples of 8)
    const int nwg = gridDim.x;
    const int qch = nwg >> 3;
    const int wgid = (blockIdx.x & 7) * qch + (blockIdx.x >> 3);
    const int MB = M >> 8;
    const int bm = wgid % MB, bn = wgid / MB;
    const int row0 = bm * 256, col0 = bn * BN;

    // ---- staging source addresses (pre-swizzled: logical g for this lane) --
    const int lrow = lane >> 2;                         // 0..15 within instr
    const int lg   = (lane & 3) ^ ((lane >> 3) & 3);    // logical 16B chunk
    const u16* aSrc = A + (long)(row0 + w * 32 + lrow) * K + lg * 8;
    const u16* bSrc = B + (long)(col0 + w * (BN / 8) + lrow) * K + lg * 8;

#define STAGE_A(dd, kt, ks) do {                                               \
        GLL16(aSrc + (long)(kt) * 64 + (ks) * 32, &lA[dd][ks][w * 1024]);      \
        GLL16(aSrc + 16 * (long)K + (long)(kt) * 64 + (ks) * 32,               \
              &lA[dd][ks][w * 1024 + 512]);                                    \
    } while (0)
#define STAGE_B(dd, kt, ks) do {                                               \
        if constexpr (BLOADS == 2) {                                           \
            GLL16(bSrc + (long)(kt) * 64 + (ks) * 32, &lB[dd][ks][w * 1024]);  \
            GLL16(bSrc + 16 * (long)K + (long)(kt) * 64 + (ks) * 32,           \
                  &lB[dd][ks][w * 1024 + 512]);                                \
        } else {                                                               \
            GLL16(bSrc + (long)(kt) * 64 + (ks) * 32, &lB[dd][ks][w * 512]);   \
        }                                                                      \
    } while (0)
#define WAIT_STEADY() do {                                                     \
        if constexpr (BLOADS == 2) VMC(6); else VMC(4);                        \
    } while (0)

    // ---- ds_read per-lane offsets (swizzled) ----
    const int agp  = g ^ ((lo >> 1) & 3);
    const int aoff = wr * 4096 + lo * 32 + agp * 8;          // + m*512
    const int boff = wc * (BN / 4) * 32 + lo * 32 + agp * 8; // + n*512

    f32x4 acc[8][4] = {};
    short8 bfr[NREP];

#define PHASE(dd, kss, mh, RB, ...) do {                                       \
        if constexpr (RB) {                                                    \
            _Pragma("unroll")                                                  \
            for (int n = 0; n < NREP; ++n)                                     \
                bfr[n] = ld16(&lB[dd][kss][boff + n * 512]);                   \
        }                                                                      \
        short8 a0 = ld16(&lA[dd][kss][aoff + ((mh) * 4 + 0) * 512]);           \
        short8 a1 = ld16(&lA[dd][kss][aoff + ((mh) * 4 + 1) * 512]);           \
        short8 a2 = ld16(&lA[dd][kss][aoff + ((mh) * 4 + 2) * 512]);           \
        short8 a3 = ld16(&lA[dd][kss][aoff + ((mh) * 4 + 3) * 512]);           \
        __VA_ARGS__;                                                           \
        __builtin_amdgcn_s_barrier();                                          \
        asm volatile("s_waitcnt lgkmcnt(0)" ::: "memory");                     \
        __builtin_amdgcn_s_setprio(1);                                         \
        _Pragma("unroll")                                                      \
        for (int n = 0; n < NREP; ++n) {                                       \
            acc[(mh) * 4 + 0][n] = __builtin_amdgcn_mfma_f32_16x16x32_bf16(    \
                a0, bfr[n], acc[(mh) * 4 + 0][n], 0, 0, 0);                    \
            acc[(mh) * 4 + 1][n] = __builtin_amdgcn_mfma_f32_16x16x32_bf16(    \
                a1, bfr[n], acc[(mh) * 4 + 1][n], 0, 0, 0);                    \
            acc[(mh) * 4 + 2][n] = __builtin_amdgcn_mfma_f32_16x16x32_bf16(    \
                a2, bfr[n], acc[(mh) * 4 + 2][n], 0, 0, 0);                    \
            acc[(mh) * 4 + 3][n] = __builtin_amdgcn_mfma_f32_16x16x32_bf16(    \
                a3, bfr[n], acc[(mh) * 4 + 3][n], 0, 0, 0);                    \
        }                                                                      \
        __builtin_amdgcn_s_setprio(0);                                         \
        __builtin_amdgcn_s_barrier();                                          \
    } while (0)

    // ---- prologue: tile0 fully + tile1 minus A_ks1 ----
    STAGE_B(0, 0, 0); STAGE_A(0, 0, 0); STAGE_B(0, 0, 1); STAGE_A(0, 0, 1);
    STAGE_B(1, 1, 0); STAGE_A(1, 1, 0); STAGE_B(1, 1, 1);
    WAIT_STEADY();
    __builtin_amdgcn_s_barrier();

    const int IT = K >> 7;   // 2 K-tiles (BK=64) per iteration
    for (int i = 0; i < IT; ++i) {
        const int t0 = 2 * i;
        const bool nl = (i < IT - 1);
        // P1: compute d0/ks0/m0-3; stage d1.A_ks1 (tile t0+1)
        PHASE(0, 0, 0, true,  { STAGE_A(1, t0 + 1, 1); });
        // P2: d0/ks0/m4-7; stage d0.B_ks0 (t0+2)
        PHASE(0, 0, 1, false, { if (nl) STAGE_B(0, t0 + 2, 0); });
        // P3: d0/ks1/m0-3; stage d0.A_ks0 (t0+2)
        PHASE(0, 1, 0, true,  { if (nl) STAGE_A(0, t0 + 2, 0); });
        // P4: d0/ks1/m4-7; stage d0.B_ks1 (t0+2); counted wait
        PHASE(0, 1, 1, false, {
            if (nl) { STAGE_B(0, t0 + 2, 1); WAIT_STEADY(); } else VMC(0);
        });
        // P5: d1/ks0/m0-3; stage d0.A_ks1 (t0+2)
        PHASE(1, 0, 0, true,  { if (nl) STAGE_A(0, t0 + 2, 1); });
        // P6: d1/ks0/m4-7; stage d1.B_ks0 (t0+3)
        PHASE(1, 0, 1, false, { if (nl) STAGE_B(1, t0 + 3, 0); });
        // P7: d1/ks1/m0-3; stage d1.A_ks0 (t0+3)
        PHASE(1, 1, 0, true,  { if (nl) STAGE_A(1, t0 + 3, 0); });
        // P8: d1/ks1/m4-7; stage d1.B_ks1 (t0+3); counted wait
        PHASE(1, 1, 1, false, {
            if (nl) { STAGE_B(1, t0 + 3, 1); WAIT_STEADY(); }
        });
    }
#undef PHASE
#undef STAGE_A
#undef STAGE_B
#undef WAIT_STEADY

    // ---- epilogue: D layout per 16x16 frag: col=lo, row=g*4+j ----
#pragma unroll
    for (int m = 0; m < 8; ++m) {
#pragma unroll
        for (int n = 0; n < NREP; ++n) {
            const int c = col0 + wc * (BN / 4) + n * 16 + lo;
            const float bs = bias[c];
#pragma unroll
            for (int j = 0; j < 4; ++j) {
                const int r = row0 + wr * 128 + m * 16 + g * 4 + j;
                const float val = acc[m][n][j] + bs;
                if constexpr (EPI == 0) {
                    outb[(long)r * N + c] = f2bf(val);
                } else if constexpr (EPI == 1) {
                    outb[(long)r * N + c] = f2bf(gelu_f(val));
                } else if constexpr (EPI == 2) {
                    outf[(long)r * N + c] = res[(long)r * N + c] + val;
                } else {  // EPI == 3: qkv scatter
                    const int part = c >> 10, cc = c & 1023;
                    const int head = cc >> 6, d = cc & 63;
                    const int bb = r >> 11, srow = r & 2047;
                    const int bh = bb * 16 + head;
                    const u16 hv = f2bf(val);
                    if (part == 0)      Qb[((long)bh * 2048 + srow) * 64 + d] = hv;
                    else if (part == 1) Kb[((long)bh * 2048 + srow) * 64 + d] = hv;
                    else                Vtb[((long)bh * 64 + d) * 2048 + srow] = hv;
                }
            }
        }
    }
}

// ---------------------------------------------------------------------------
// Causal flash attention, 32x32x16 MFMA structure (unchanged from R1).
// ---------------------------------------------------------------------------
__global__ __launch_bounds__(256) void attn_fwd32(
    const u16* __restrict__ Q, const u16* __restrict__ K,
    const u16* __restrict__ Vt, u16* __restrict__ O) {
    const int bh = blockIdx.x;
    const int qt = 15 - blockIdx.y;          // heavy q-tiles dispatch first
    const int wave = threadIdx.x >> 6, lane = threadIdx.x & 63;
    const int lq = lane & 31, hi = lane >> 5;
    const int qw = qt * 128 + wave * 32;

    const u16* Qp = Q + ((long)bh * 2048 + qw) * 64;
    const u16* Kp = K + (long)bh * 2048 * 64;
    const u16* Vp = Vt + (long)bh * 64 * 2048;

    short8 qf[4];
#pragma unroll
    for (int ks = 0; ks < 4; ++ks)
        qf[ks] = ld16(Qp + lq * 64 + ks * 16 + hi * 8);

    f32x16 o0 = {}, o1 = {};
    float m = -1e30f, l = 0.f;
    const float scale = 0.125f;
    const int q_abs = qw + lq;
    const int nkv = qw + 32;

    for (int kv0 = 0; kv0 < nkv; kv0 += 64) {
        f32x16 s0 = {}, s1 = {};
        const u16* Kr = Kp + (long)(kv0 + lq) * 64 + hi * 8;
#pragma unroll
        for (int ks = 0; ks < 4; ++ks)
            s0 = __builtin_amdgcn_mfma_f32_32x32x16_bf16(
                ld16(Kr + ks * 16), qf[ks], s0, 0, 0, 0);
        const u16* Kr2 = Kr + 32 * 64;
#pragma unroll
        for (int ks = 0; ks < 4; ++ks)
            s1 = __builtin_amdgcn_mfma_f32_32x32x16_bf16(
                ld16(Kr2 + ks * 16), qf[ks], s1, 0, 0, 0);

        float mt = -1e30f;
        if (kv0 + 64 >= nkv) {               // diagonal tile
#pragma unroll
            for (int r = 0; r < 16; ++r) {
                const int kv = kv0 + (r & 3) + 8 * (r >> 2) + 4 * hi;
                float v = s0[r] * scale;
                if (kv > q_abs) v = -1e30f;
                s0[r] = v; mt = fmaxf(mt, v);
                v = s1[r] * scale;
                if (kv + 32 > q_abs) v = -1e30f;
                s1[r] = v; mt = fmaxf(mt, v);
            }
        } else {
#pragma unroll
            for (int r = 0; r < 16; ++r) {
                s0[r] *= scale; s1[r] *= scale;
                mt = fmaxf(mt, fmaxf(s0[r], s1[r]));
            }
        }
        mt = fmaxf(mt, __shfl_xor(mt, 32));

        const float mn = fmaxf(m, mt);
        const float corr = __expf(m - mn);
        m = mn;
        float ps = 0.f;
#pragma unroll
        for (int r = 0; r < 16; ++r) {
            s0[r] = __expf(s0[r] - mn); ps += s0[r];
            s1[r] = __expf(s1[r] - mn); ps += s1[r];
        }
        l = l * corr + ps;
        o0 *= corr; o1 *= corr;

        short8 pf[4];
#pragma unroll
        for (int c = 0; c < 4; ++c) {
            const f32x16& src = (c >> 1) ? s1 : s0;
            const int b = (c & 1) * 8;
            const unsigned A0 = pk2(src[b + 0], src[b + 1]);
            const unsigned A1 = pk2(src[b + 2], src[b + 3]);
            const unsigned B0 = pk2(src[b + 4], src[b + 5]);
            const unsigned B1 = pk2(src[b + 6], src[b + 7]);
            const unsigned S0 = hi ? A0 : B0;
            const unsigned S1 = hi ? A1 : B1;
            const unsigned R0 = (unsigned)__shfl_xor((int)S0, 32);
            const unsigned R1 = (unsigned)__shfl_xor((int)S1, 32);
            union { unsigned u[4]; short8 v; } fr;
            fr.u[0] = hi ? R0 : A0;
            fr.u[1] = hi ? R1 : A1;
            fr.u[2] = hi ? B0 : R0;
            fr.u[3] = hi ? B1 : R1;
            pf[c] = fr.v;
        }

        const u16* Vr = Vp + (long)lq * 2048 + kv0 + hi * 8;
#pragma unroll
        for (int c = 0; c < 4; ++c) {
            o0 = __builtin_amdgcn_mfma_f32_32x32x16_bf16(
                ld16(Vr + c * 16), pf[c], o0, 0, 0, 0);
            o1 = __builtin_amdgcn_mfma_f32_32x32x16_bf16(
                ld16(Vr + 32 * 2048 + c * 16), pf[c], o1, 0, 0, 0);
        }
    }

    l += __shfl_xor(l, 32);
    const float inv = 1.f / l;
    const int bb = bh >> 4, h = bh & 15;
    u16* Orow = O + ((long)(bb * 2048 + qw + lq)) * 1024 + h * 64;
#pragma unroll
    for (int k4 = 0; k4 < 4; ++k4) {
        u16x4 w0, w1;
#pragma unroll
        for (int j = 0; j < 4; ++j) {
            w0[j] = f2bf(o0[k4 * 4 + j] * inv);
            w1[j] = f2bf(o1[k4 * 4 + j] * inv);
        }
        *reinterpret_cast<u16x4*>(Orow + 8 * k4 + 4 * hi)      = w0;
        *reinterpret_cast<u16x4*>(Orow + 32 + 8 * k4 + 4 * hi) = w1;
    }
}

// ---------------------------------------------------------------------------
// launch
// ---------------------------------------------------------------------------
extern "C" void kernel_launch(void* const* d_in, const int* in_sizes, int n_in,
                              void* d_out, int out_size, void* d_ws, size_t ws_size,
                              hipStream_t stream) {
    const float* x      = (const float*)d_in[0];
    const float* ln1_g  = (const float*)d_in[1];
    const float* ln1_b  = (const float*)d_in[2];
    const float* qkv_w  = (const float*)d_in[3];
    const float* qkv_b  = (const float*)d_in[4];
    const float* out_w  = (const float*)d_in[5];
    const float* out_b  = (const float*)d_in[6];
    const float* ln2_g  = (const float*)d_in[7];
    const float* ln2_b  = (const float*)d_in[8];
    const float* fc1_w  = (const float*)d_in[9];
    const float* fc1_b  = (const float*)d_in[10];
    const float* fc2_w  = (const float*)d_in[11];
    const float* fc2_b  = (const float*)d_in[12];
    float* out = (float*)d_out;

    const size_t MB = 1024ull * 1024ull;
    if (ws_size < 120 * MB) return;
    char* ws = (char*)d_ws;
    u16* wqkv = (u16*)(ws + 0);        // 6 MB
    u16* wout = (u16*)(ws + 6 * MB);   // 2 MB
    u16* wfc1 = (u16*)(ws + 8 * MB);   // 8 MB
    u16* wfc2 = (u16*)(ws + 16 * MB);  // 8 MB
    u16* hbuf = (u16*)(ws + 24 * MB);  // 16 MB  (LN output, bf16)
    u16* obuf = (u16*)(ws + 40 * MB);  // 16 MB  (attn output, bf16)
    u16* Qb   = (u16*)(ws + 56 * MB);  // 16 MB
    u16* Kb   = (u16*)(ws + 72 * MB);  // 16 MB
    u16* Vtb  = (u16*)(ws + 88 * MB);  // 16 MB
    u16* gbuf = (u16*)(ws + 56 * MB);  // 64 MB  (FFN hidden, reuses Q/K/Vt)

    cvt_f32_bf16<<<3072, 256, 0, stream>>>(qkv_w, wqkv, 3072 * 1024 / 4);
    cvt_f32_bf16<<<1024, 256, 0, stream>>>(out_w, wout, 1024 * 1024 / 4);
    cvt_f32_bf16<<<4096, 256, 0, stream>>>(fc1_w, wfc1, 4096 * 1024 / 4);
    cvt_f32_bf16<<<4096, 256, 0, stream>>>(fc2_w, wfc2, 1024 * 4096 / 4);

    ln_bf16<<<8192, 256, 0, stream>>>(x, ln1_g, ln1_b, hbuf);
    // QKV: M=8192, N=3072, K=1024 -> grid 32*12 = 384
    gemm8<256, 3><<<dim3(384), 512, 0, stream>>>(hbuf, wqkv, qkv_b, nullptr,
                                                 nullptr, nullptr, Qb, Kb, Vtb,
                                                 8192, 3072, 1024);
    attn_fwd32<<<dim3(64, 16), 256, 0, stream>>>(Qb, Kb, Vtb, obuf);
    // out-proj: N=1024 -> BN=128, grid 32*8 = 256
    gemm8<128, 2><<<dim3(256), 512, 0, stream>>>(obuf, wout, out_b, x, out,
                                                 nullptr, nullptr, nullptr, nullptr,
                                                 8192, 1024, 1024);
    ln_bf16<<<8192, 256, 0, stream>>>(out, ln2_g, ln2_b, hbuf);
    // FC1: N=4096 -> grid 32*16 = 512
    gemm8<256, 1><<<dim3(512), 512, 0, stream>>>(hbuf, wfc1, fc1_b, nullptr,
                                                 nullptr, gbuf, nullptr, nullptr,
                                                 nullptr, 8192, 4096, 1024);
    // FC2: N=1024, K=4096 -> BN=128, grid 256
    gemm8<128, 2><<<dim3(256), 512, 0, stream>>>(gbuf, wfc2, fc2_b, out, out,
                                                 nullptr, nullptr, nullptr, nullptr,
                                                 8192, 1024, 4096);
}

// Round 4
// 561.922 us; speedup vs baseline: 1.0374x; 1.0374x over previous
//
#include <hip/hip_runtime.h>
#include <math.h>

// ---------------------------------------------------------------------------
// Types / helpers
// ---------------------------------------------------------------------------
using u16 = unsigned short;
typedef __attribute__((ext_vector_type(8))) short short8;   // 8 x bf16 (raw bits)
typedef __attribute__((ext_vector_type(4))) float f32x4;
typedef __attribute__((ext_vector_type(16))) float f32x16;
typedef __attribute__((ext_vector_type(4))) u16 u16x4;

#define DEV __device__ __forceinline__

DEV u16 f2bf(float f) {                       // f32 -> bf16, round-nearest-even
    unsigned u = __float_as_uint(f);
    u += 0x7fffu + ((u >> 16) & 1u);
    return (u16)(u >> 16);
}
DEV float bf2f(u16 h) { return __uint_as_float(((unsigned)h) << 16); }

DEV short8 ld16(const u16* p) { return *reinterpret_cast<const short8*>(p); }

DEV float gelu_f(float x) { return 0.5f * x * (1.f + erff(x * 0.70710678118654752f)); }

DEV unsigned pk2(float a, float b) {          // two f32 -> packed bf16x2
    return (unsigned)f2bf(a) | ((unsigned)f2bf(b) << 16);
}

// async global->LDS, 16B per lane, LDS dest = wave-uniform base + lane*16
#define GLL16(gp, lp)                                                          \
    __builtin_amdgcn_global_load_lds(                                          \
        (const __attribute__((address_space(1))) void*)(gp),                   \
        (__attribute__((address_space(3))) void*)(lp), 16, 0, 0)

#define VMC(n) asm volatile("s_waitcnt vmcnt(" #n ")" ::: "memory")

// ---------------------------------------------------------------------------
// fp32 -> bf16 convert (weights)
// ---------------------------------------------------------------------------
__global__ void cvt_f32_bf16(const float* __restrict__ in, u16* __restrict__ out, int n4) {
    int i = blockIdx.x * 256 + threadIdx.x;
    if (i >= n4) return;
    float4 v = reinterpret_cast<const float4*>(in)[i];
    u16x4 o;
    o.x = f2bf(v.x); o.y = f2bf(v.y); o.z = f2bf(v.z); o.w = f2bf(v.w);
    reinterpret_cast<u16x4*>(out)[i] = o;
}

// ---------------------------------------------------------------------------
// LayerNorm (fp32 in) -> bf16 out.  One block per row, 256 threads x 4 floats.
// ---------------------------------------------------------------------------
__global__ __launch_bounds__(256) void ln_bf16(const float* __restrict__ x,
                                               const float* __restrict__ gm,
                                               const float* __restrict__ bt,
                                               u16* __restrict__ out) {
    const int row = blockIdx.x, tid = threadIdx.x;
    const float4 v = reinterpret_cast<const float4*>(x + (long)row * 1024)[tid];
    float s  = v.x + v.y + v.z + v.w;
    float sq = v.x * v.x + v.y * v.y + v.z * v.z + v.w * v.w;
#pragma unroll
    for (int off = 1; off <= 32; off <<= 1) {
        s  += __shfl_xor(s, off);
        sq += __shfl_xor(sq, off);
    }
    __shared__ float ss[4], ssq[4];
    const int wave = tid >> 6, lane = tid & 63;
    if (lane == 0) { ss[wave] = s; ssq[wave] = sq; }
    __syncthreads();
    s  = ss[0] + ss[1] + ss[2] + ss[3];
    sq = ssq[0] + ssq[1] + ssq[2] + ssq[3];
    const float mu   = s * (1.f / 1024.f);
    const float var  = sq * (1.f / 1024.f) - mu * mu;
    const float rstd = rsqrtf(var + 1e-5f);
    const float4 g4 = reinterpret_cast<const float4*>(gm)[tid];
    const float4 b4 = reinterpret_cast<const float4*>(bt)[tid];
    u16x4 o;
    o.x = f2bf((v.x - mu) * rstd * g4.x + b4.x);
    o.y = f2bf((v.y - mu) * rstd * g4.y + b4.y);
    o.z = f2bf((v.z - mu) * rstd * g4.z + b4.z);
    o.w = f2bf((v.w - mu) * rstd * g4.w + b4.w);
    reinterpret_cast<u16x4*>(out + (long)row * 1024)[tid] = o;
}

// ---------------------------------------------------------------------------
// 8-phase 256xBN GEMM (m201-style): C[M,N] = A[M,K] @ B[N,K]^T + bias.
// BM=256, BK=64, 512 threads = 8 waves (2M x 4N), per-wave C = 128 x (BN/4).
// MFMA operand order (bfr, af): D frag is ROW-major per lane (lane&15 = out
// row within frag, (lane>>4)*4+j = 4 consecutive out cols) -> vectorized
// 8/16-byte epilogue stores (full-line writes, no L2 RMW).
// EPI: 0 = bf16 out, 1 = bf16 gelu out, 2 = fp32 out + residual,
//      3 = scatter into Q [BH,S,64], K [BH,S,64], Vt [BH,64,S]
// ---------------------------------------------------------------------------
template <int BN, int EPI>
__global__ __launch_bounds__(512, 2) void gemm8(
    const u16* __restrict__ A, const u16* __restrict__ B,
    const float* __restrict__ bias, const float* res, float* outf,
    u16* __restrict__ outb, u16* __restrict__ Qb, u16* __restrict__ Kb,
    u16* __restrict__ Vtb, int M, int N, int K) {
    constexpr int NREP   = BN / 64;    // B n-frags per wave (4 or 2)
    constexpr int BLOADS = BN / 128;   // gload_lds instrs per wave per B-half

    __shared__ u16 lA[2][2][8192];       // [dbuf][ks][256 rows x 32]
    __shared__ u16 lB[2][2][BN * 32];    // [dbuf][ks][BN rows x 32]

    const int tid = threadIdx.x;
    const int w = tid >> 6, lane = tid & 63;
    const int lo = lane & 15, g = lane >> 4;
    const int wr = w >> 2, wc = w & 3;

    // bijective XCD swizzle (all grids here are multiples of 8)
    const int nwg = gridDim.x;
    const int qch = nwg >> 3;
    const int wgid = (blockIdx.x & 7) * qch + (blockIdx.x >> 3);
    const int MB = M >> 8;
    const int bm = wgid % MB, bn = wgid / MB;
    const int row0 = bm * 256, col0 = bn * BN;

    // ---- staging source addresses (pre-swizzled: logical g for this lane) --
    const int lrow = lane >> 2;                         // 0..15 within instr
    const int lg   = (lane & 3) ^ ((lane >> 3) & 3);    // logical 16B chunk
    const u16* aSrc = A + (long)(row0 + w * 32 + lrow) * K + lg * 8;
    const u16* bSrc = B + (long)(col0 + w * (BN / 8) + lrow) * K + lg * 8;

#define STAGE_A(dd, kt, ks) do {                                               \
        GLL16(aSrc + (long)(kt) * 64 + (ks) * 32, &lA[dd][ks][w * 1024]);      \
        GLL16(aSrc + 16 * (long)K + (long)(kt) * 64 + (ks) * 32,               \
              &lA[dd][ks][w * 1024 + 512]);                                    \
    } while (0)
#define STAGE_B(dd, kt, ks) do {                                               \
        if constexpr (BLOADS == 2) {                                           \
            GLL16(bSrc + (long)(kt) * 64 + (ks) * 32, &lB[dd][ks][w * 1024]);  \
            GLL16(bSrc + 16 * (long)K + (long)(kt) * 64 + (ks) * 32,           \
                  &lB[dd][ks][w * 1024 + 512]);                                \
        } else {                                                               \
            GLL16(bSrc + (long)(kt) * 64 + (ks) * 32, &lB[dd][ks][w * 512]);   \
        }                                                                      \
    } while (0)
#define WAIT_STEADY() do {                                                     \
        if constexpr (BLOADS == 2) VMC(6); else VMC(4);                        \
    } while (0)

    // ---- ds_read per-lane offsets (swizzled) ----
    const int agp  = g ^ ((lo >> 1) & 3);
    const int aoff = wr * 4096 + lo * 32 + agp * 8;          // + m*512
    const int boff = wc * (BN / 4) * 32 + lo * 32 + agp * 8; // + n*512

    f32x4 acc[8][4] = {};
    short8 bfr[NREP];

#define PHASE(dd, kss, mh, RB, ...) do {                                       \
        if constexpr (RB) {                                                    \
            _Pragma("unroll")                                                  \
            for (int n = 0; n < NREP; ++n)                                     \
                bfr[n] = ld16(&lB[dd][kss][boff + n * 512]);                   \
        }                                                                      \
        short8 a0 = ld16(&lA[dd][kss][aoff + ((mh) * 4 + 0) * 512]);           \
        short8 a1 = ld16(&lA[dd][kss][aoff + ((mh) * 4 + 1) * 512]);           \
        short8 a2 = ld16(&lA[dd][kss][aoff + ((mh) * 4 + 2) * 512]);           \
        short8 a3 = ld16(&lA[dd][kss][aoff + ((mh) * 4 + 3) * 512]);           \
        __VA_ARGS__;                                                           \
        __builtin_amdgcn_s_barrier();                                          \
        asm volatile("s_waitcnt lgkmcnt(0)" ::: "memory");                     \
        __builtin_amdgcn_s_setprio(1);                                         \
        _Pragma("unroll")                                                      \
        for (int n = 0; n < NREP; ++n) {                                       \
            acc[(mh) * 4 + 0][n] = __builtin_amdgcn_mfma_f32_16x16x32_bf16(    \
                bfr[n], a0, acc[(mh) * 4 + 0][n], 0, 0, 0);                    \
            acc[(mh) * 4 + 1][n] = __builtin_amdgcn_mfma_f32_16x16x32_bf16(    \
                bfr[n], a1, acc[(mh) * 4 + 1][n], 0, 0, 0);                    \
            acc[(mh) * 4 + 2][n] = __builtin_amdgcn_mfma_f32_16x16x32_bf16(    \
                bfr[n], a2, acc[(mh) * 4 + 2][n], 0, 0, 0);                    \
            acc[(mh) * 4 + 3][n] = __builtin_amdgcn_mfma_f32_16x16x32_bf16(    \
                bfr[n], a3, acc[(mh) * 4 + 3][n], 0, 0, 0);                    \
        }                                                                      \
        __builtin_amdgcn_s_setprio(0);                                         \
        __builtin_amdgcn_s_barrier();                                          \
    } while (0)

    // ---- prologue: tile0 fully + tile1 minus A_ks1 ----
    STAGE_B(0, 0, 0); STAGE_A(0, 0, 0); STAGE_B(0, 0, 1); STAGE_A(0, 0, 1);
    STAGE_B(1, 1, 0); STAGE_A(1, 1, 0); STAGE_B(1, 1, 1);
    WAIT_STEADY();
    __builtin_amdgcn_s_barrier();

    const int IT = K >> 7;   // 2 K-tiles (BK=64) per iteration
    for (int i = 0; i < IT; ++i) {
        const int t0 = 2 * i;
        const bool nl = (i < IT - 1);
        PHASE(0, 0, 0, true,  { STAGE_A(1, t0 + 1, 1); });
        PHASE(0, 0, 1, false, { if (nl) STAGE_B(0, t0 + 2, 0); });
        PHASE(0, 1, 0, true,  { if (nl) STAGE_A(0, t0 + 2, 0); });
        PHASE(0, 1, 1, false, {
            if (nl) { STAGE_B(0, t0 + 2, 1); WAIT_STEADY(); } else VMC(0);
        });
        PHASE(1, 0, 0, true,  { if (nl) STAGE_A(0, t0 + 2, 1); });
        PHASE(1, 0, 1, false, { if (nl) STAGE_B(1, t0 + 3, 0); });
        PHASE(1, 1, 0, true,  { if (nl) STAGE_A(1, t0 + 3, 0); });
        PHASE(1, 1, 1, false, {
            if (nl) { STAGE_B(1, t0 + 3, 1); WAIT_STEADY(); }
        });
    }
#undef PHASE
#undef STAGE_A
#undef STAGE_B
#undef WAIT_STEADY

    // ---- epilogue: row-major frags: row = ...+lo, cols = cb + j (4 wide) ---
#pragma unroll
    for (int n = 0; n < NREP; ++n) {
        const int cb = col0 + wc * (BN / 4) + n * 16 + g * 4;
        const float4 b4 = *reinterpret_cast<const float4*>(&bias[cb]);
#pragma unroll
        for (int m = 0; m < 8; ++m) {
            const int r = row0 + wr * 128 + m * 16 + lo;
            const float v0 = acc[m][n][0] + b4.x;
            const float v1 = acc[m][n][1] + b4.y;
            const float v2 = acc[m][n][2] + b4.z;
            const float v3 = acc[m][n][3] + b4.w;
            if constexpr (EPI == 0) {
                u16x4 o = {f2bf(v0), f2bf(v1), f2bf(v2), f2bf(v3)};
                *reinterpret_cast<u16x4*>(&outb[(long)r * N + cb]) = o;
            } else if constexpr (EPI == 1) {
                u16x4 o = {f2bf(gelu_f(v0)), f2bf(gelu_f(v1)),
                           f2bf(gelu_f(v2)), f2bf(gelu_f(v3))};
                *reinterpret_cast<u16x4*>(&outb[(long)r * N + cb]) = o;
            } else if constexpr (EPI == 2) {
                const float4 rr = *reinterpret_cast<const float4*>(&res[(long)r * N + cb]);
                float4 o = {rr.x + v0, rr.y + v1, rr.z + v2, rr.w + v3};
                *reinterpret_cast<float4*>(&outf[(long)r * N + cb]) = o;
            } else {  // EPI == 3: qkv scatter
                const int part = cb >> 10, cc = cb & 1023;
                const int head = cc >> 6, d = cc & 63;
                const int bb = r >> 11, srow = r & 2047;
                const int bh = bb * 16 + head;
                if (part == 0) {
                    u16x4 o = {f2bf(v0), f2bf(v1), f2bf(v2), f2bf(v3)};
                    *reinterpret_cast<u16x4*>(&Qb[((long)bh * 2048 + srow) * 64 + d]) = o;
                } else if (part == 1) {
                    u16x4 o = {f2bf(v0), f2bf(v1), f2bf(v2), f2bf(v3)};
                    *reinterpret_cast<u16x4*>(&Kb[((long)bh * 2048 + srow) * 64 + d]) = o;
                } else {
                    Vtb[((long)bh * 64 + d + 0) * 2048 + srow] = f2bf(v0);
                    Vtb[((long)bh * 64 + d + 1) * 2048 + srow] = f2bf(v1);
                    Vtb[((long)bh * 64 + d + 2) * 2048 + srow] = f2bf(v2);
                    Vtb[((long)bh * 64 + d + 3) * 2048 + srow] = f2bf(v3);
                }
            }
        }
    }
}

// ---------------------------------------------------------------------------
// Causal flash attention, 32x32x16 MFMA structure (unchanged).
// ---------------------------------------------------------------------------
__global__ __launch_bounds__(256) void attn_fwd32(
    const u16* __restrict__ Q, const u16* __restrict__ K,
    const u16* __restrict__ Vt, u16* __restrict__ O) {
    const int bh = blockIdx.x;
    const int qt = 15 - blockIdx.y;          // heavy q-tiles dispatch first
    const int wave = threadIdx.x >> 6, lane = threadIdx.x & 63;
    const int lq = lane & 31, hi = lane >> 5;
    const int qw = qt * 128 + wave * 32;

    const u16* Qp = Q + ((long)bh * 2048 + qw) * 64;
    const u16* Kp = K + (long)bh * 2048 * 64;
    const u16* Vp = Vt + (long)bh * 64 * 2048;

    short8 qf[4];
#pragma unroll
    for (int ks = 0; ks < 4; ++ks)
        qf[ks] = ld16(Qp + lq * 64 + ks * 16 + hi * 8);

    f32x16 o0 = {}, o1 = {};
    float m = -1e30f, l = 0.f;
    const float scale = 0.125f;
    const int q_abs = qw + lq;
    const int nkv = qw + 32;

    for (int kv0 = 0; kv0 < nkv; kv0 += 64) {
        f32x16 s0 = {}, s1 = {};
        const u16* Kr = Kp + (long)(kv0 + lq) * 64 + hi * 8;
#pragma unroll
        for (int ks = 0; ks < 4; ++ks)
            s0 = __builtin_amdgcn_mfma_f32_32x32x16_bf16(
                ld16(Kr + ks * 16), qf[ks], s0, 0, 0, 0);
        const u16* Kr2 = Kr + 32 * 64;
#pragma unroll
        for (int ks = 0; ks < 4; ++ks)
            s1 = __builtin_amdgcn_mfma_f32_32x32x16_bf16(
                ld16(Kr2 + ks * 16), qf[ks], s1, 0, 0, 0);

        float mt = -1e30f;
        if (kv0 + 64 >= nkv) {               // diagonal tile
#pragma unroll
            for (int r = 0; r < 16; ++r) {
                const int kv = kv0 + (r & 3) + 8 * (r >> 2) + 4 * hi;
                float v = s0[r] * scale;
                if (kv > q_abs) v = -1e30f;
                s0[r] = v; mt = fmaxf(mt, v);
                v = s1[r] * scale;
                if (kv + 32 > q_abs) v = -1e30f;
                s1[r] = v; mt = fmaxf(mt, v);
            }
        } else {
#pragma unroll
            for (int r = 0; r < 16; ++r) {
                s0[r] *= scale; s1[r] *= scale;
                mt = fmaxf(mt, fmaxf(s0[r], s1[r]));
            }
        }
        mt = fmaxf(mt, __shfl_xor(mt, 32));

        const float mn = fmaxf(m, mt);
        const float corr = __expf(m - mn);
        m = mn;
        float ps = 0.f;
#pragma unroll
        for (int r = 0; r < 16; ++r) {
            s0[r] = __expf(s0[r] - mn); ps += s0[r];
            s1[r] = __expf(s1[r] - mn); ps += s1[r];
        }
        l = l * corr + ps;
        o0 *= corr; o1 *= corr;

        short8 pf[4];
#pragma unroll
        for (int c = 0; c < 4; ++c) {
            const f32x16& src = (c >> 1) ? s1 : s0;
            const int b = (c & 1) * 8;
            const unsigned A0 = pk2(src[b + 0], src[b + 1]);
            const unsigned A1 = pk2(src[b + 2], src[b + 3]);
            const unsigned B0 = pk2(src[b + 4], src[b + 5]);
            const unsigned B1 = pk2(src[b + 6], src[b + 7]);
            const unsigned S0 = hi ? A0 : B0;
            const unsigned S1 = hi ? A1 : B1;
            const unsigned R0 = (unsigned)__shfl_xor((int)S0, 32);
            const unsigned R1 = (unsigned)__shfl_xor((int)S1, 32);
            union { unsigned u[4]; short8 v; } fr;
            fr.u[0] = hi ? R0 : A0;
            fr.u[1] = hi ? R1 : A1;
            fr.u[2] = hi ? B0 : R0;
            fr.u[3] = hi ? B1 : R1;
            pf[c] = fr.v;
        }

        const u16* Vr = Vp + (long)lq * 2048 + kv0 + hi * 8;
#pragma unroll
        for (int c = 0; c < 4; ++c) {
            o0 = __builtin_amdgcn_mfma_f32_32x32x16_bf16(
                ld16(Vr + c * 16), pf[c], o0, 0, 0, 0);
            o1 = __builtin_amdgcn_mfma_f32_32x32x16_bf16(
                ld16(Vr + 32 * 2048 + c * 16), pf[c], o1, 0, 0, 0);
        }
    }

    l += __shfl_xor(l, 32);
    const float inv = 1.f / l;
    const int bb = bh >> 4, h = bh & 15;
    u16* Orow = O + ((long)(bb * 2048 + qw + lq)) * 1024 + h * 64;
#pragma unroll
    for (int k4 = 0; k4 < 4; ++k4) {
        u16x4 w0, w1;
#pragma unroll
        for (int j = 0; j < 4; ++j) {
            w0[j] = f2bf(o0[k4 * 4 + j] * inv);
            w1[j] = f2bf(o1[k4 * 4 + j] * inv);
        }
        *reinterpret_cast<u16x4*>(Orow + 8 * k4 + 4 * hi)      = w0;
        *reinterpret_cast<u16x4*>(Orow + 32 + 8 * k4 + 4 * hi) = w1;
    }
}

// ---------------------------------------------------------------------------
// launch
// ---------------------------------------------------------------------------
extern "C" void kernel_launch(void* const* d_in, const int* in_sizes, int n_in,
                              void* d_out, int out_size, void* d_ws, size_t ws_size,
                              hipStream_t stream) {
    const float* x      = (const float*)d_in[0];
    const float* ln1_g  = (const float*)d_in[1];
    const float* ln1_b  = (const float*)d_in[2];
    const float* qkv_w  = (const float*)d_in[3];
    const float* qkv_b  = (const float*)d_in[4];
    const float* out_w  = (const float*)d_in[5];
    const float* out_b  = (const float*)d_in[6];
    const float* ln2_g  = (const float*)d_in[7];
    const float* ln2_b  = (const float*)d_in[8];
    const float* fc1_w  = (const float*)d_in[9];
    const float* fc1_b  = (const float*)d_in[10];
    const float* fc2_w  = (const float*)d_in[11];
    const float* fc2_b  = (const float*)d_in[12];
    float* out = (float*)d_out;

    const size_t MB = 1024ull * 1024ull;
    if (ws_size < 120 * MB) return;
    char* ws = (char*)d_ws;
    u16* wqkv = (u16*)(ws + 0);        // 6 MB
    u16* wout = (u16*)(ws + 6 * MB);   // 2 MB
    u16* wfc1 = (u16*)(ws + 8 * MB);   // 8 MB
    u16* wfc2 = (u16*)(ws + 16 * MB);  // 8 MB
    u16* hbuf = (u16*)(ws + 24 * MB);  // 16 MB  (LN output, bf16)
    u16* obuf = (u16*)(ws + 40 * MB);  // 16 MB  (attn output, bf16)
    u16* Qb   = (u16*)(ws + 56 * MB);  // 16 MB
    u16* Kb   = (u16*)(ws + 72 * MB);  // 16 MB
    u16* Vtb  = (u16*)(ws + 88 * MB);  // 16 MB
    u16* gbuf = (u16*)(ws + 56 * MB);  // 64 MB  (FFN hidden, reuses Q/K/Vt)

    cvt_f32_bf16<<<3072, 256, 0, stream>>>(qkv_w, wqkv, 3072 * 1024 / 4);
    cvt_f32_bf16<<<1024, 256, 0, stream>>>(out_w, wout, 1024 * 1024 / 4);
    cvt_f32_bf16<<<4096, 256, 0, stream>>>(fc1_w, wfc1, 4096 * 1024 / 4);
    cvt_f32_bf16<<<4096, 256, 0, stream>>>(fc2_w, wfc2, 1024 * 4096 / 4);

    ln_bf16<<<8192, 256, 0, stream>>>(x, ln1_g, ln1_b, hbuf);
    // QKV: M=8192, N=3072, K=1024 -> grid 32*12 = 384
    gemm8<256, 3><<<dim3(384), 512, 0, stream>>>(hbuf, wqkv, qkv_b, nullptr,
                                                 nullptr, nullptr, Qb, Kb, Vtb,
                                                 8192, 3072, 1024);
    attn_fwd32<<<dim3(64, 16), 256, 0, stream>>>(Qb, Kb, Vtb, obuf);
    // out-proj: N=1024 -> BN=128, grid 32*8 = 256
    gemm8<128, 2><<<dim3(256), 512, 0, stream>>>(obuf, wout, out_b, x, out,
                                                 nullptr, nullptr, nullptr, nullptr,
                                                 8192, 1024, 1024);
    ln_bf16<<<8192, 256, 0, stream>>>(out, ln2_g, ln2_b, hbuf);
    // FC1: N=4096 -> grid 32*16 = 512
    gemm8<256, 1><<<dim3(512), 512, 0, stream>>>(hbuf, wfc1, fc1_b, nullptr,
                                                 nullptr, gbuf, nullptr, nullptr,
                                                 nullptr, 8192, 4096, 1024);
    // FC2: N=1024, K=4096 -> BN=128, grid 256
    gemm8<128, 2><<<dim3(256), 512, 0, stream>>>(gbuf, wfc2, fc2_b, out, out,
                                                 nullptr, nullptr, nullptr, nullptr,
                                                 8192, 1024, 4096);
}

// Round 5
// 511.679 us; speedup vs baseline: 1.1393x; 1.0982x over previous
//
#include <hip/hip_runtime.h>
#include <math.h>

// ---------------------------------------------------------------------------
// Types / helpers
// ---------------------------------------------------------------------------
using u16 = unsigned short;
typedef __attribute__((ext_vector_type(8))) short short8;   // 8 x bf16 (raw bits)
typedef __attribute__((ext_vector_type(4))) float f32x4;
typedef __attribute__((ext_vector_type(16))) float f32x16;
typedef __attribute__((ext_vector_type(4))) u16 u16x4;

#define DEV __device__ __forceinline__

DEV u16 f2bf(float f) {                       // f32 -> bf16, round-nearest-even
    unsigned u = __float_as_uint(f);
    u += 0x7fffu + ((u >> 16) & 1u);
    return (u16)(u >> 16);
}
DEV float bf2f(u16 h) { return __uint_as_float(((unsigned)h) << 16); }

DEV short8 ld16(const u16* p) { return *reinterpret_cast<const short8*>(p); }

DEV float gelu_f(float x) { return 0.5f * x * (1.f + erff(x * 0.70710678118654752f)); }

DEV unsigned pk2(float a, float b) {          // packed bf16x2 via HW cvt (RNE)
    unsigned r;
    asm("v_cvt_pk_bf16_f32 %0, %1, %2" : "=v"(r) : "v"(a), "v"(b));
    return r;
}

// async global->LDS, 16B per lane, LDS dest = wave-uniform base + lane*16
#define GLL16(gp, lp)                                                          \
    __builtin_amdgcn_global_load_lds(                                          \
        (const __attribute__((address_space(1))) void*)(gp),                   \
        (__attribute__((address_space(3))) void*)(lp), 16, 0, 0)

#define VMC(n) asm volatile("s_waitcnt vmcnt(" #n ")" ::: "memory")

// ---------------------------------------------------------------------------
// fp32 -> bf16 convert (weights)
// ---------------------------------------------------------------------------
__global__ void cvt_f32_bf16(const float* __restrict__ in, u16* __restrict__ out, int n4) {
    int i = blockIdx.x * 256 + threadIdx.x;
    if (i >= n4) return;
    float4 v = reinterpret_cast<const float4*>(in)[i];
    u16x4 o;
    o.x = f2bf(v.x); o.y = f2bf(v.y); o.z = f2bf(v.z); o.w = f2bf(v.w);
    reinterpret_cast<u16x4*>(out)[i] = o;
}

// ---------------------------------------------------------------------------
// LayerNorm (fp32 in) -> bf16 out.  One block per row, 256 threads x 4 floats.
// ---------------------------------------------------------------------------
__global__ __launch_bounds__(256) void ln_bf16(const float* __restrict__ x,
                                               const float* __restrict__ gm,
                                               const float* __restrict__ bt,
                                               u16* __restrict__ out) {
    const int row = blockIdx.x, tid = threadIdx.x;
    const float4 v = reinterpret_cast<const float4*>(x + (long)row * 1024)[tid];
    float s  = v.x + v.y + v.z + v.w;
    float sq = v.x * v.x + v.y * v.y + v.z * v.z + v.w * v.w;
#pragma unroll
    for (int off = 1; off <= 32; off <<= 1) {
        s  += __shfl_xor(s, off);
        sq += __shfl_xor(sq, off);
    }
    __shared__ float ss[4], ssq[4];
    const int wave = tid >> 6, lane = tid & 63;
    if (lane == 0) { ss[wave] = s; ssq[wave] = sq; }
    __syncthreads();
    s  = ss[0] + ss[1] + ss[2] + ss[3];
    sq = ssq[0] + ssq[1] + ssq[2] + ssq[3];
    const float mu   = s * (1.f / 1024.f);
    const float var  = sq * (1.f / 1024.f) - mu * mu;
    const float rstd = rsqrtf(var + 1e-5f);
    const float4 g4 = reinterpret_cast<const float4*>(gm)[tid];
    const float4 b4 = reinterpret_cast<const float4*>(bt)[tid];
    u16x4 o;
    o.x = f2bf((v.x - mu) * rstd * g4.x + b4.x);
    o.y = f2bf((v.y - mu) * rstd * g4.y + b4.y);
    o.z = f2bf((v.z - mu) * rstd * g4.z + b4.z);
    o.w = f2bf((v.w - mu) * rstd * g4.w + b4.w);
    reinterpret_cast<u16x4*>(out + (long)row * 1024)[tid] = o;
}

// ---------------------------------------------------------------------------
// 8-phase 256xBN GEMM (m201-style): C[M,N] = A[M,K] @ B[N,K]^T + bias.
// BM=256, BK=64, 512 threads = 8 waves (2M x 4N), per-wave C = 128 x (BN/4).
// Block order bn-FASTEST: consecutive wgids (co-resident on one XCD via the
// swizzle) share the A (activation) panel -> A fetched ~once from HBM.
// EPI: 0 = bf16 out, 1 = bf16 gelu out, 2 = fp32 out + residual,
//      3 = scatter into Q [BH,S,64], K [BH,S,64], Vt [BH,64,S]
// ---------------------------------------------------------------------------
template <int BN, int EPI>
__global__ __launch_bounds__(512, 2) void gemm8(
    const u16* __restrict__ A, const u16* __restrict__ B,
    const float* __restrict__ bias, const float* res, float* outf,
    u16* __restrict__ outb, u16* __restrict__ Qb, u16* __restrict__ Kb,
    u16* __restrict__ Vtb, int M, int N, int K) {
    constexpr int NREP   = BN / 64;    // B n-frags per wave (4 or 2)
    constexpr int BLOADS = BN / 128;   // gload_lds instrs per wave per B-half

    __shared__ u16 lA[2][2][8192];       // [dbuf][ks][256 rows x 32]
    __shared__ u16 lB[2][2][BN * 32];    // [dbuf][ks][BN rows x 32]

    const int tid = threadIdx.x;
    const int w = tid >> 6, lane = tid & 63;
    const int lo = lane & 15, g = lane >> 4;
    const int wr = w >> 2, wc = w & 3;

    // bijective XCD swizzle (all grids here are multiples of 8)
    const int nwg = gridDim.x;
    const int qch = nwg >> 3;
    const int wgid = (blockIdx.x & 7) * qch + (blockIdx.x >> 3);
    const int NBb = N / BN;
    const int bm = wgid / NBb, bn = wgid % NBb;   // bn fastest: share A-panel
    const int row0 = bm * 256, col0 = bn * BN;

    // ---- staging source addresses (pre-swizzled: logical g for this lane) --
    const int lrow = lane >> 2;                         // 0..15 within instr
    const int lg   = (lane & 3) ^ ((lane >> 3) & 3);    // logical 16B chunk
    const u16* aSrc = A + (long)(row0 + w * 32 + lrow) * K + lg * 8;
    const u16* bSrc = B + (long)(col0 + w * (BN / 8) + lrow) * K + lg * 8;

#define STAGE_A(dd, kt, ks) do {                                               \
        GLL16(aSrc + (long)(kt) * 64 + (ks) * 32, &lA[dd][ks][w * 1024]);      \
        GLL16(aSrc + 16 * (long)K + (long)(kt) * 64 + (ks) * 32,               \
              &lA[dd][ks][w * 1024 + 512]);                                    \
    } while (0)
#define STAGE_B(dd, kt, ks) do {                                               \
        if constexpr (BLOADS == 2) {                                           \
            GLL16(bSrc + (long)(kt) * 64 + (ks) * 32, &lB[dd][ks][w * 1024]);  \
            GLL16(bSrc + 16 * (long)K + (long)(kt) * 64 + (ks) * 32,           \
                  &lB[dd][ks][w * 1024 + 512]);                                \
        } else {                                                               \
            GLL16(bSrc + (long)(kt) * 64 + (ks) * 32, &lB[dd][ks][w * 512]);   \
        }                                                                      \
    } while (0)
#define WAIT_STEADY() do {                                                     \
        if constexpr (BLOADS == 2) VMC(6); else VMC(4);                        \
    } while (0)

    // ---- ds_read per-lane offsets (swizzled) ----
    const int agp  = g ^ ((lo >> 1) & 3);
    const int aoff = wr * 4096 + lo * 32 + agp * 8;          // + m*512
    const int boff = wc * (BN / 4) * 32 + lo * 32 + agp * 8; // + n*512

    f32x4 acc[8][4] = {};
    short8 bfr[NREP];

#define PHASE(dd, kss, mh, RB, ...) do {                                       \
        if constexpr (RB) {                                                    \
            _Pragma("unroll")                                                  \
            for (int n = 0; n < NREP; ++n)                                     \
                bfr[n] = ld16(&lB[dd][kss][boff + n * 512]);                   \
        }                                                                      \
        short8 a0 = ld16(&lA[dd][kss][aoff + ((mh) * 4 + 0) * 512]);           \
        short8 a1 = ld16(&lA[dd][kss][aoff + ((mh) * 4 + 1) * 512]);           \
        short8 a2 = ld16(&lA[dd][kss][aoff + ((mh) * 4 + 2) * 512]);           \
        short8 a3 = ld16(&lA[dd][kss][aoff + ((mh) * 4 + 3) * 512]);           \
        __VA_ARGS__;                                                           \
        __builtin_amdgcn_s_barrier();                                          \
        asm volatile("s_waitcnt lgkmcnt(0)" ::: "memory");                     \
        __builtin_amdgcn_s_setprio(1);                                         \
        _Pragma("unroll")                                                      \
        for (int n = 0; n < NREP; ++n) {                                       \
            acc[(mh) * 4 + 0][n] = __builtin_amdgcn_mfma_f32_16x16x32_bf16(    \
                bfr[n], a0, acc[(mh) * 4 + 0][n], 0, 0, 0);                    \
            acc[(mh) * 4 + 1][n] = __builtin_amdgcn_mfma_f32_16x16x32_bf16(    \
                bfr[n], a1, acc[(mh) * 4 + 1][n], 0, 0, 0);                    \
            acc[(mh) * 4 + 2][n] = __builtin_amdgcn_mfma_f32_16x16x32_bf16(    \
                bfr[n], a2, acc[(mh) * 4 + 2][n], 0, 0, 0);                    \
            acc[(mh) * 4 + 3][n] = __builtin_amdgcn_mfma_f32_16x16x32_bf16(    \
                bfr[n], a3, acc[(mh) * 4 + 3][n], 0, 0, 0);                    \
        }                                                                      \
        __builtin_amdgcn_s_setprio(0);                                         \
        __builtin_amdgcn_s_barrier();                                          \
    } while (0)

    // ---- prologue: tile0 fully + tile1 minus A_ks1 ----
    STAGE_B(0, 0, 0); STAGE_A(0, 0, 0); STAGE_B(0, 0, 1); STAGE_A(0, 0, 1);
    STAGE_B(1, 1, 0); STAGE_A(1, 1, 0); STAGE_B(1, 1, 1);
    WAIT_STEADY();
    __builtin_amdgcn_s_barrier();

    const int IT = K >> 7;   // 2 K-tiles (BK=64) per iteration
    for (int i = 0; i < IT; ++i) {
        const int t0 = 2 * i;
        const bool nl = (i < IT - 1);
        PHASE(0, 0, 0, true,  { STAGE_A(1, t0 + 1, 1); });
        PHASE(0, 0, 1, false, { if (nl) STAGE_B(0, t0 + 2, 0); });
        PHASE(0, 1, 0, true,  { if (nl) STAGE_A(0, t0 + 2, 0); });
        PHASE(0, 1, 1, false, {
            if (nl) { STAGE_B(0, t0 + 2, 1); WAIT_STEADY(); } else VMC(0);
        });
        PHASE(1, 0, 0, true,  { if (nl) STAGE_A(0, t0 + 2, 1); });
        PHASE(1, 0, 1, false, { if (nl) STAGE_B(1, t0 + 3, 0); });
        PHASE(1, 1, 0, true,  { if (nl) STAGE_A(1, t0 + 3, 0); });
        PHASE(1, 1, 1, false, {
            if (nl) { STAGE_B(1, t0 + 3, 1); WAIT_STEADY(); }
        });
    }
#undef PHASE
#undef STAGE_A
#undef STAGE_B
#undef WAIT_STEADY

    // ---- epilogue: row-major frags: row = ...+lo, cols = cb + j (4 wide) ---
#pragma unroll
    for (int n = 0; n < NREP; ++n) {
        const int cb = col0 + wc * (BN / 4) + n * 16 + g * 4;
        const float4 b4 = *reinterpret_cast<const float4*>(&bias[cb]);
#pragma unroll
        for (int m = 0; m < 8; ++m) {
            const int r = row0 + wr * 128 + m * 16 + lo;
            const float v0 = acc[m][n][0] + b4.x;
            const float v1 = acc[m][n][1] + b4.y;
            const float v2 = acc[m][n][2] + b4.z;
            const float v3 = acc[m][n][3] + b4.w;
            if constexpr (EPI == 0) {
                u16x4 o = {f2bf(v0), f2bf(v1), f2bf(v2), f2bf(v3)};
                *reinterpret_cast<u16x4*>(&outb[(long)r * N + cb]) = o;
            } else if constexpr (EPI == 1) {
                u16x4 o = {f2bf(gelu_f(v0)), f2bf(gelu_f(v1)),
                           f2bf(gelu_f(v2)), f2bf(gelu_f(v3))};
                *reinterpret_cast<u16x4*>(&outb[(long)r * N + cb]) = o;
            } else if constexpr (EPI == 2) {
                const float4 rr = *reinterpret_cast<const float4*>(&res[(long)r * N + cb]);
                float4 o = {rr.x + v0, rr.y + v1, rr.z + v2, rr.w + v3};
                *reinterpret_cast<float4*>(&outf[(long)r * N + cb]) = o;
            } else {  // EPI == 3: qkv scatter
                const int part = cb >> 10, cc = cb & 1023;
                const int head = cc >> 6, d = cc & 63;
                const int bb = r >> 11, srow = r & 2047;
                const int bh = bb * 16 + head;
                if (part == 0) {
                    u16x4 o = {f2bf(v0), f2bf(v1), f2bf(v2), f2bf(v3)};
                    *reinterpret_cast<u16x4*>(&Qb[((long)bh * 2048 + srow) * 64 + d]) = o;
                } else if (part == 1) {
                    u16x4 o = {f2bf(v0), f2bf(v1), f2bf(v2), f2bf(v3)};
                    *reinterpret_cast<u16x4*>(&Kb[((long)bh * 2048 + srow) * 64 + d]) = o;
                } else {
                    Vtb[((long)bh * 64 + d + 0) * 2048 + srow] = f2bf(v0);
                    Vtb[((long)bh * 64 + d + 1) * 2048 + srow] = f2bf(v1);
                    Vtb[((long)bh * 64 + d + 2) * 2048 + srow] = f2bf(v2);
                    Vtb[((long)bh * 64 + d + 3) * 2048 + srow] = f2bf(v3);
                }
            }
        }
    }
}

// ---------------------------------------------------------------------------
// Causal flash attention, 32x32x16 MFMA.  Pair-balanced: block (bh, p) runs
// tiles 15-p then p (uniform total kv work).  V loads hoisted before the
// softmax (latency hides under exp chain); P packing via v_cvt_pk_bf16_f32.
// ---------------------------------------------------------------------------
__global__ __launch_bounds__(256) void attn_fwd32(
    const u16* __restrict__ Q, const u16* __restrict__ K,
    const u16* __restrict__ Vt, u16* __restrict__ O) {
    const int bh = blockIdx.x;
    const int p = blockIdx.y;                // pair index 0..7
    const int wave = threadIdx.x >> 6, lane = threadIdx.x & 63;
    const int lq = lane & 31, hi = lane >> 5;

    const u16* Kp = K + (long)bh * 2048 * 64;
    const u16* Vp = Vt + (long)bh * 64 * 2048;
    const int bb = bh >> 4, h = bh & 15;
    const float scale = 0.125f;              // 1/sqrt(64)

#pragma unroll
    for (int sp = 0; sp < 2; ++sp) {
        const int qt = sp ? p : (15 - p);    // heavy strip first
        const int qw = qt * 128 + wave * 32;
        const u16* Qp = Q + ((long)bh * 2048 + qw) * 64;

        short8 qf[4];
#pragma unroll
        for (int ks = 0; ks < 4; ++ks)
            qf[ks] = ld16(Qp + lq * 64 + ks * 16 + hi * 8);

        f32x16 o0 = {}, o1 = {};
        float m = -1e30f, l = 0.f;
        const int q_abs = qw + lq;
        const int nkv = qw + 32;

        for (int kv0 = 0; kv0 < nkv; kv0 += 64) {
            // ---- S^T = K * Q^T  (two 32-kv tiles) ----
            f32x16 s0 = {}, s1 = {};
            const u16* Kr = Kp + (long)(kv0 + lq) * 64 + hi * 8;
#pragma unroll
            for (int ks = 0; ks < 4; ++ks)
                s0 = __builtin_amdgcn_mfma_f32_32x32x16_bf16(
                    ld16(Kr + ks * 16), qf[ks], s0, 0, 0, 0);
            const u16* Kr2 = Kr + 32 * 64;
#pragma unroll
            for (int ks = 0; ks < 4; ++ks)
                s1 = __builtin_amdgcn_mfma_f32_32x32x16_bf16(
                    ld16(Kr2 + ks * 16), qf[ks], s1, 0, 0, 0);

            // ---- V prefetch (latency hides under softmax below) ----
            const u16* Vr = Vp + (long)lq * 2048 + kv0 + hi * 8;
            short8 vf0[4], vf1[4];
#pragma unroll
            for (int c = 0; c < 4; ++c) {
                vf0[c] = ld16(Vr + c * 16);
                vf1[c] = ld16(Vr + 32 * 2048 + c * 16);
            }

            // ---- scale (+ causal mask on the diagonal iteration) ----
            float mt = -1e30f;
            if (kv0 + 64 >= nkv) {           // diagonal tile
#pragma unroll
                for (int r = 0; r < 16; ++r) {
                    const int kv = kv0 + (r & 3) + 8 * (r >> 2) + 4 * hi;
                    float v = s0[r] * scale;
                    if (kv > q_abs) v = -1e30f;
                    s0[r] = v; mt = fmaxf(mt, v);
                    v = s1[r] * scale;
                    if (kv + 32 > q_abs) v = -1e30f;
                    s1[r] = v; mt = fmaxf(mt, v);
                }
            } else {
#pragma unroll
                for (int r = 0; r < 16; ++r) {
                    s0[r] *= scale; s1[r] *= scale;
                    mt = fmaxf(mt, fmaxf(s0[r], s1[r]));
                }
            }
            mt = fmaxf(mt, __shfl_xor(mt, 32));

            const float mn = fmaxf(m, mt);
            const float corr = __expf(m - mn);
            m = mn;
            float ps = 0.f;
#pragma unroll
            for (int r = 0; r < 16; ++r) {
                s0[r] = __expf(s0[r] - mn); ps += s0[r];
                s1[r] = __expf(s1[r] - mn); ps += s1[r];
            }
            l = l * corr + ps;
            o0 *= corr; o1 *= corr;

            // ---- build P^T B-frags (4 chunks of kv16), 2 shuffles each ----
            short8 pf[4];
#pragma unroll
            for (int c = 0; c < 4; ++c) {
                const f32x16& src = (c >> 1) ? s1 : s0;
                const int b = (c & 1) * 8;
                const unsigned A0 = pk2(src[b + 0], src[b + 1]);
                const unsigned A1 = pk2(src[b + 2], src[b + 3]);
                const unsigned B0 = pk2(src[b + 4], src[b + 5]);
                const unsigned B1 = pk2(src[b + 6], src[b + 7]);
                const unsigned S0 = hi ? A0 : B0;
                const unsigned S1 = hi ? A1 : B1;
                const unsigned R0 = (unsigned)__shfl_xor((int)S0, 32);
                const unsigned R1 = (unsigned)__shfl_xor((int)S1, 32);
                union { unsigned u[4]; short8 v; } fr;
                fr.u[0] = hi ? R0 : A0;
                fr.u[1] = hi ? R1 : A1;
                fr.u[2] = hi ? B0 : R0;
                fr.u[3] = hi ? B1 : R1;
                pf[c] = fr.v;
            }

            // ---- O^T += Vt * P^T ----
#pragma unroll
            for (int c = 0; c < 4; ++c) {
                o0 = __builtin_amdgcn_mfma_f32_32x32x16_bf16(
                    vf0[c], pf[c], o0, 0, 0, 0);
                o1 = __builtin_amdgcn_mfma_f32_32x32x16_bf16(
                    vf1[c], pf[c], o1, 0, 0, 0);
            }
        }

        // ---- finish: combine l across lane pair, normalize, store ----
        l += __shfl_xor(l, 32);
        const float inv = 1.f / l;
        u16* Orow = O + ((long)(bb * 2048 + qw + lq)) * 1024 + h * 64;
#pragma unroll
        for (int k4 = 0; k4 < 4; ++k4) {
            u16x4 w0, w1;
#pragma unroll
            for (int j = 0; j < 4; ++j) {
                w0[j] = f2bf(o0[k4 * 4 + j] * inv);
                w1[j] = f2bf(o1[k4 * 4 + j] * inv);
            }
            *reinterpret_cast<u16x4*>(Orow + 8 * k4 + 4 * hi)      = w0;
            *reinterpret_cast<u16x4*>(Orow + 32 + 8 * k4 + 4 * hi) = w1;
        }
    }
}

// ---------------------------------------------------------------------------
// launch
// ---------------------------------------------------------------------------
extern "C" void kernel_launch(void* const* d_in, const int* in_sizes, int n_in,
                              void* d_out, int out_size, void* d_ws, size_t ws_size,
                              hipStream_t stream) {
    const float* x      = (const float*)d_in[0];
    const float* ln1_g  = (const float*)d_in[1];
    const float* ln1_b  = (const float*)d_in[2];
    const float* qkv_w  = (const float*)d_in[3];
    const float* qkv_b  = (const float*)d_in[4];
    const float* out_w  = (const float*)d_in[5];
    const float* out_b  = (const float*)d_in[6];
    const float* ln2_g  = (const float*)d_in[7];
    const float* ln2_b  = (const float*)d_in[8];
    const float* fc1_w  = (const float*)d_in[9];
    const float* fc1_b  = (const float*)d_in[10];
    const float* fc2_w  = (const float*)d_in[11];
    const float* fc2_b  = (const float*)d_in[12];
    float* out = (float*)d_out;

    const size_t MB = 1024ull * 1024ull;
    if (ws_size < 120 * MB) return;
    char* ws = (char*)d_ws;
    u16* wqkv = (u16*)(ws + 0);        // 6 MB
    u16* wout = (u16*)(ws + 6 * MB);   // 2 MB
    u16* wfc1 = (u16*)(ws + 8 * MB);   // 8 MB
    u16* wfc2 = (u16*)(ws + 16 * MB);  // 8 MB
    u16* hbuf = (u16*)(ws + 24 * MB);  // 16 MB  (LN output, bf16)
    u16* obuf = (u16*)(ws + 40 * MB);  // 16 MB  (attn output, bf16)
    u16* Qb   = (u16*)(ws + 56 * MB);  // 16 MB
    u16* Kb   = (u16*)(ws + 72 * MB);  // 16 MB
    u16* Vtb  = (u16*)(ws + 88 * MB);  // 16 MB
    u16* gbuf = (u16*)(ws + 56 * MB);  // 64 MB  (FFN hidden, reuses Q/K/Vt)

    cvt_f32_bf16<<<3072, 256, 0, stream>>>(qkv_w, wqkv, 3072 * 1024 / 4);
    cvt_f32_bf16<<<1024, 256, 0, stream>>>(out_w, wout, 1024 * 1024 / 4);
    cvt_f32_bf16<<<4096, 256, 0, stream>>>(fc1_w, wfc1, 4096 * 1024 / 4);
    cvt_f32_bf16<<<4096, 256, 0, stream>>>(fc2_w, wfc2, 1024 * 4096 / 4);

    ln_bf16<<<8192, 256, 0, stream>>>(x, ln1_g, ln1_b, hbuf);
    // QKV: M=8192, N=3072, K=1024 -> grid 32*12 = 384
    gemm8<256, 3><<<dim3(384), 512, 0, stream>>>(hbuf, wqkv, qkv_b, nullptr,
                                                 nullptr, nullptr, Qb, Kb, Vtb,
                                                 8192, 3072, 1024);
    attn_fwd32<<<dim3(64, 8), 256, 0, stream>>>(Qb, Kb, Vtb, obuf);
    // out-proj: N=1024 -> BN=128, grid 32*8 = 256
    gemm8<128, 2><<<dim3(256), 512, 0, stream>>>(obuf, wout, out_b, x, out,
                                                 nullptr, nullptr, nullptr, nullptr,
                                                 8192, 1024, 1024);
    ln_bf16<<<8192, 256, 0, stream>>>(out, ln2_g, ln2_b, hbuf);
    // FC1: N=4096 -> grid 32*16 = 512
    gemm8<256, 1><<<dim3(512), 512, 0, stream>>>(hbuf, wfc1, fc1_b, nullptr,
                                                 nullptr, gbuf, nullptr, nullptr,
                                                 nullptr, 8192, 4096, 1024);
    // FC2: N=1024, K=4096 -> BN=128, grid 256
    gemm8<128, 2><<<dim3(256), 512, 0, stream>>>(gbuf, wfc2, fc2_b, out, out,
                                                 nullptr, nullptr, nullptr, nullptr,
                                                 8192, 1024, 4096);
}

// Round 6
// 452.785 us; speedup vs baseline: 1.2875x; 1.1301x over previous
//
#include <hip/hip_runtime.h>
#include <math.h>

// ---------------------------------------------------------------------------
// Types / helpers
// ---------------------------------------------------------------------------
using u16 = unsigned short;
typedef __attribute__((ext_vector_type(8))) short short8;   // 8 x bf16 (raw bits)
typedef __attribute__((ext_vector_type(4))) float f32x4;
typedef __attribute__((ext_vector_type(16))) float f32x16;
typedef __attribute__((ext_vector_type(4))) u16 u16x4;

#define DEV __device__ __forceinline__

DEV u16 f2bf(float f) {                       // f32 -> bf16, round-nearest-even
    unsigned u = __float_as_uint(f);
    u += 0x7fffu + ((u >> 16) & 1u);
    return (u16)(u >> 16);
}
DEV float bf2f(u16 h) { return __uint_as_float(((unsigned)h) << 16); }

DEV short8 ld16(const u16* p) { return *reinterpret_cast<const short8*>(p); }

DEV float gelu_f(float x) { return 0.5f * x * (1.f + erff(x * 0.70710678118654752f)); }

DEV unsigned pk2(float a, float b) {          // packed bf16x2 via HW cvt (RNE)
    unsigned r;
    asm("v_cvt_pk_bf16_f32 %0, %1, %2" : "=v"(r) : "v"(a), "v"(b));
    return r;
}

// async global->LDS, 16B per lane, LDS dest = wave-uniform base + lane*16
#define GLL16(gp, lp)                                                          \
    __builtin_amdgcn_global_load_lds(                                          \
        (const __attribute__((address_space(1))) void*)(gp),                   \
        (__attribute__((address_space(3))) void*)(lp), 16, 0, 0)

// ---------------------------------------------------------------------------
// fp32 -> bf16 convert (weights)
// ---------------------------------------------------------------------------
__global__ void cvt_f32_bf16(const float* __restrict__ in, u16* __restrict__ out, int n4) {
    int i = blockIdx.x * 256 + threadIdx.x;
    if (i >= n4) return;
    float4 v = reinterpret_cast<const float4*>(in)[i];
    u16x4 o;
    o.x = f2bf(v.x); o.y = f2bf(v.y); o.z = f2bf(v.z); o.w = f2bf(v.w);
    reinterpret_cast<u16x4*>(out)[i] = o;
}

// ---------------------------------------------------------------------------
// LayerNorm (fp32 in) -> bf16 out.  One block per row, 256 threads x 4 floats.
// ---------------------------------------------------------------------------
__global__ __launch_bounds__(256) void ln_bf16(const float* __restrict__ x,
                                               const float* __restrict__ gm,
                                               const float* __restrict__ bt,
                                               u16* __restrict__ out) {
    const int row = blockIdx.x, tid = threadIdx.x;
    const float4 v = reinterpret_cast<const float4*>(x + (long)row * 1024)[tid];
    float s  = v.x + v.y + v.z + v.w;
    float sq = v.x * v.x + v.y * v.y + v.z * v.z + v.w * v.w;
#pragma unroll
    for (int off = 1; off <= 32; off <<= 1) {
        s  += __shfl_xor(s, off);
        sq += __shfl_xor(sq, off);
    }
    __shared__ float ss[4], ssq[4];
    const int wave = tid >> 6, lane = tid & 63;
    if (lane == 0) { ss[wave] = s; ssq[wave] = sq; }
    __syncthreads();
    s  = ss[0] + ss[1] + ss[2] + ss[3];
    sq = ssq[0] + ssq[1] + ssq[2] + ssq[3];
    const float mu   = s * (1.f / 1024.f);
    const float var  = sq * (1.f / 1024.f) - mu * mu;
    const float rstd = rsqrtf(var + 1e-5f);
    const float4 g4 = reinterpret_cast<const float4*>(gm)[tid];
    const float4 b4 = reinterpret_cast<const float4*>(bt)[tid];
    u16x4 o;
    o.x = f2bf((v.x - mu) * rstd * g4.x + b4.x);
    o.y = f2bf((v.y - mu) * rstd * g4.y + b4.y);
    o.z = f2bf((v.z - mu) * rstd * g4.z + b4.z);
    o.w = f2bf((v.w - mu) * rstd * g4.w + b4.w);
    reinterpret_cast<u16x4*>(out + (long)row * 1024)[tid] = o;
}

// ---------------------------------------------------------------------------
// m97-style GEMM: C[M,N] = A[M,K] @ B[N,K]^T + bias.  128x128 tile, BK=32,
// 4 waves (2x2), 4x4 16x16x32 MFMA frags/wave, global_load_lds staging with
// XOR-swizzled LDS (pre-swizzled source + swizzled ds_read; 0 bank conflicts).
// 3 blocks/CU: cross-block overlap hides barrier/latency stalls.
// Block order: bn-fastest within XCD-chunked wgid (A-panel L2 sharing).
// MFMA (bfr, af) order -> row-major D frag -> vectorized epilogue stores.
// EPI: 0 = bf16 out, 1 = bf16 gelu out, 2 = fp32 out + residual,
//      3 = QKV: Q/K direct u16x4; V via in-LDS 128x128 transpose -> Vt.
// ---------------------------------------------------------------------------
#define TS(c, r) ((c) * 128 + (((((r) >> 3) ^ ((c) & 15))) << 3) + ((r) & 7))

template <int EPI>
__global__ __launch_bounds__(256, 3) void gemm_bt(
    const u16* __restrict__ A, const u16* __restrict__ B,
    const float* __restrict__ bias, const float* res, float* outf,
    u16* __restrict__ outb, u16* __restrict__ Qb, u16* __restrict__ Kb,
    u16* __restrict__ Vtb, int M, int N, int K) {
    constexpr int SHSZ = (EPI == 3) ? 16384 : 8192;
    __shared__ u16 shpool[SHSZ];
    u16* As = shpool;            // [128][32]
    u16* Bs = shpool + 4096;     // [128][32]

    const int tid = threadIdx.x;
    const int wave = tid >> 6, lane = tid & 63;
    const int lo = lane & 15, g = lane >> 4;
    const int wr = wave >> 1, wc = wave & 1;

    // XCD-chunked bijective swizzle; bn fastest (co-resident blocks share A)
    const int nwg = gridDim.x, chunk = nwg >> 3;
    const int wgid = (blockIdx.x & 7) * chunk + (blockIdx.x >> 3);
    const int NB = N >> 7;
    const int bm = wgid / NB, bn = wgid % NB;
    const int row0 = bm * 128, col0 = bn * 128;

    // staging source (pre-swizzled logical chunk so linear LDS dest = swizzled)
    const int lrow = lane >> 2;
    const int lg   = (lane & 3) ^ ((lane >> 3) & 3);
    const u16* Ag = A + (long)(row0 + wave * 16 + lrow) * K + lg * 8;
    const u16* Bg = B + (long)(col0 + wave * 16 + lrow) * K + lg * 8;
    u16* Al = As + wave * 512;
    u16* Bl = Bs + wave * 512;

    const int agp = g ^ ((lo >> 1) & 3);      // swizzled ds_read chunk
    f32x4 acc[4][4] = {};

    for (int k0 = 0; k0 < K; k0 += 32) {
        GLL16(Ag, Al);
        GLL16(Ag + 64 * (long)K, Al + 2048);
        GLL16(Bg, Bl);
        GLL16(Bg + 64 * (long)K, Bl + 2048);
        Ag += 32; Bg += 32;
        __syncthreads();          // drains vmcnt: staging landed
        short8 af[4], bfr[4];
#pragma unroll
        for (int m = 0; m < 4; ++m)
            af[m] = ld16(&As[(wr * 64 + m * 16 + lo) * 32 + agp * 8]);
#pragma unroll
        for (int n = 0; n < 4; ++n)
            bfr[n] = ld16(&Bs[(wc * 64 + n * 16 + lo) * 32 + agp * 8]);
        __builtin_amdgcn_s_setprio(1);
#pragma unroll
        for (int m = 0; m < 4; ++m)
#pragma unroll
            for (int n = 0; n < 4; ++n)
                acc[m][n] = __builtin_amdgcn_mfma_f32_16x16x32_bf16(
                    bfr[n], af[m], acc[m][n], 0, 0, 0);
        __builtin_amdgcn_s_setprio(0);
        __syncthreads();          // reads done before next-tile overwrite
    }

    // ---- epilogue: row-major frags: row = ...+lo, 4 consecutive cols ----
    if constexpr (EPI == 3) {
        if (col0 >= 2048) {       // V block: transpose via LDS, coalesced Vt
#pragma unroll
            for (int n = 0; n < 4; ++n) {
                const int cb = wc * 64 + n * 16 + g * 4;
                const float4 b4 = *reinterpret_cast<const float4*>(&bias[col0 + cb]);
#pragma unroll
                for (int m = 0; m < 4; ++m) {
                    const int rl = wr * 64 + m * 16 + lo;
                    shpool[TS(cb + 0, rl)] = f2bf(acc[m][n][0] + b4.x);
                    shpool[TS(cb + 1, rl)] = f2bf(acc[m][n][1] + b4.y);
                    shpool[TS(cb + 2, rl)] = f2bf(acc[m][n][2] + b4.z);
                    shpool[TS(cb + 3, rl)] = f2bf(acc[m][n][3] + b4.w);
                }
            }
            __syncthreads();
            const int c = tid >> 1, half = tid & 1;
            const int dcol = (col0 - 2048) + c;
            const int head = dcol >> 6, d = dcol & 63;
            const int bb = row0 >> 11;
            u16* dst = Vtb + ((long)(bb * 16 + head) * 64 + d) * 2048 +
                       (row0 & 2047) + half * 64;
            const u16* srcb = shpool + c * 128;
#pragma unroll
            for (int i = 0; i < 8; ++i) {
                const int pc = (half * 8 + i) ^ (c & 15);
                *reinterpret_cast<short8*>(dst + i * 8) =
                    *reinterpret_cast<const short8*>(srcb + pc * 8);
            }
            return;
        }
    }
#pragma unroll
    for (int n = 0; n < 4; ++n) {
        const int cb = col0 + wc * 64 + n * 16 + g * 4;
        const float4 b4 = *reinterpret_cast<const float4*>(&bias[cb]);
#pragma unroll
        for (int m = 0; m < 4; ++m) {
            const int r = row0 + wr * 64 + m * 16 + lo;
            const float v0 = acc[m][n][0] + b4.x;
            const float v1 = acc[m][n][1] + b4.y;
            const float v2 = acc[m][n][2] + b4.z;
            const float v3 = acc[m][n][3] + b4.w;
            if constexpr (EPI == 0) {
                u16x4 o = {f2bf(v0), f2bf(v1), f2bf(v2), f2bf(v3)};
                *reinterpret_cast<u16x4*>(&outb[(long)r * N + cb]) = o;
            } else if constexpr (EPI == 1) {
                u16x4 o = {f2bf(gelu_f(v0)), f2bf(gelu_f(v1)),
                           f2bf(gelu_f(v2)), f2bf(gelu_f(v3))};
                *reinterpret_cast<u16x4*>(&outb[(long)r * N + cb]) = o;
            } else if constexpr (EPI == 2) {
                const float4 rr = *reinterpret_cast<const float4*>(&res[(long)r * N + cb]);
                float4 o = {rr.x + v0, rr.y + v1, rr.z + v2, rr.w + v3};
                *reinterpret_cast<float4*>(&outf[(long)r * N + cb]) = o;
            } else {  // EPI == 3, Q/K block
                const int part = cb >> 10, cc = cb & 1023;
                const int head = cc >> 6, d = cc & 63;
                const int bb = r >> 11, srow = r & 2047;
                const int bh = bb * 16 + head;
                u16x4 o = {f2bf(v0), f2bf(v1), f2bf(v2), f2bf(v3)};
                u16* base = (part == 0) ? Qb : Kb;
                *reinterpret_cast<u16x4*>(&base[((long)bh * 2048 + srow) * 64 + d]) = o;
            }
        }
    }
}

// ---------------------------------------------------------------------------
// Causal flash attention, 32x32x16 MFMA.  Pair-balanced blocks; V prefetch
// before softmax; defer-max (THR=8) skips O/l rescale on most iterations;
// setprio around MFMA clusters; P packing via v_cvt_pk_bf16_f32.
// ---------------------------------------------------------------------------
__global__ __launch_bounds__(256) void attn_fwd32(
    const u16* __restrict__ Q, const u16* __restrict__ K,
    const u16* __restrict__ Vt, u16* __restrict__ O) {
    const int bh = blockIdx.x;
    const int p = blockIdx.y;                // pair index 0..7
    const int wave = threadIdx.x >> 6, lane = threadIdx.x & 63;
    const int lq = lane & 31, hi = lane >> 5;

    const u16* Kp = K + (long)bh * 2048 * 64;
    const u16* Vp = Vt + (long)bh * 64 * 2048;
    const int bb = bh >> 4, h = bh & 15;
    const float scale = 0.125f;              // 1/sqrt(64)

#pragma unroll
    for (int sp = 0; sp < 2; ++sp) {
        const int qt = sp ? p : (15 - p);    // heavy strip first
        const int qw = qt * 128 + wave * 32;
        const u16* Qp = Q + ((long)bh * 2048 + qw) * 64;

        short8 qf[4];
#pragma unroll
        for (int ks = 0; ks < 4; ++ks)
            qf[ks] = ld16(Qp + lq * 64 + ks * 16 + hi * 8);

        f32x16 o0 = {}, o1 = {};
        float m = -1e30f, l = 0.f;
        const int q_abs = qw + lq;
        const int nkv = qw + 32;

        for (int kv0 = 0; kv0 < nkv; kv0 += 64) {
            // ---- S^T = K * Q^T  (two 32-kv tiles) ----
            f32x16 s0 = {}, s1 = {};
            const u16* Kr = Kp + (long)(kv0 + lq) * 64 + hi * 8;
            __builtin_amdgcn_s_setprio(1);
#pragma unroll
            for (int ks = 0; ks < 4; ++ks)
                s0 = __builtin_amdgcn_mfma_f32_32x32x16_bf16(
                    ld16(Kr + ks * 16), qf[ks], s0, 0, 0, 0);
            const u16* Kr2 = Kr + 32 * 64;
#pragma unroll
            for (int ks = 0; ks < 4; ++ks)
                s1 = __builtin_amdgcn_mfma_f32_32x32x16_bf16(
                    ld16(Kr2 + ks * 16), qf[ks], s1, 0, 0, 0);
            __builtin_amdgcn_s_setprio(0);

            // ---- V prefetch (latency hides under softmax below) ----
            const u16* Vr = Vp + (long)lq * 2048 + kv0 + hi * 8;
            short8 vf0[4], vf1[4];
#pragma unroll
            for (int c = 0; c < 4; ++c) {
                vf0[c] = ld16(Vr + c * 16);
                vf1[c] = ld16(Vr + 32 * 2048 + c * 16);
            }

            // ---- scale (+ causal mask on the diagonal iteration) ----
            float mt = -1e30f;
            if (kv0 + 64 >= nkv) {           // diagonal tile
#pragma unroll
                for (int r = 0; r < 16; ++r) {
                    const int kv = kv0 + (r & 3) + 8 * (r >> 2) + 4 * hi;
                    float v = s0[r] * scale;
                    if (kv > q_abs) v = -1e30f;
                    s0[r] = v; mt = fmaxf(mt, v);
                    v = s1[r] * scale;
                    if (kv + 32 > q_abs) v = -1e30f;
                    s1[r] = v; mt = fmaxf(mt, v);
                }
            } else {
#pragma unroll
                for (int r = 0; r < 16; ++r) {
                    s0[r] *= scale; s1[r] *= scale;
                    mt = fmaxf(mt, fmaxf(s0[r], s1[r]));
                }
            }
            mt = fmaxf(mt, __shfl_xor(mt, 32));

            // ---- defer-max: rescale only when max grew past threshold ----
            if (!__all(mt <= m + 8.f)) {
                const float mn = fmaxf(m, mt);
                const float corr = __expf(m - mn);
                m = mn;
                l *= corr;
                o0 *= corr; o1 *= corr;
            }
            float ps = 0.f;
#pragma unroll
            for (int r = 0; r < 16; ++r) {
                s0[r] = __expf(s0[r] - m); ps += s0[r];
                s1[r] = __expf(s1[r] - m); ps += s1[r];
            }
            l += ps;

            // ---- build P^T B-frags (4 chunks of kv16), 2 shuffles each ----
            short8 pf[4];
#pragma unroll
            for (int c = 0; c < 4; ++c) {
                const f32x16& src = (c >> 1) ? s1 : s0;
                const int b = (c & 1) * 8;
                const unsigned A0 = pk2(src[b + 0], src[b + 1]);
                const unsigned A1 = pk2(src[b + 2], src[b + 3]);
                const unsigned B0 = pk2(src[b + 4], src[b + 5]);
                const unsigned B1 = pk2(src[b + 6], src[b + 7]);
                const unsigned S0 = hi ? A0 : B0;
                const unsigned S1 = hi ? A1 : B1;
                const unsigned R0 = (unsigned)__shfl_xor((int)S0, 32);
                const unsigned R1 = (unsigned)__shfl_xor((int)S1, 32);
                union { unsigned u[4]; short8 v; } fr;
                fr.u[0] = hi ? R0 : A0;
                fr.u[1] = hi ? R1 : A1;
                fr.u[2] = hi ? B0 : R0;
                fr.u[3] = hi ? B1 : R1;
                pf[c] = fr.v;
            }

            // ---- O^T += Vt * P^T ----
            __builtin_amdgcn_s_setprio(1);
#pragma unroll
            for (int c = 0; c < 4; ++c) {
                o0 = __builtin_amdgcn_mfma_f32_32x32x16_bf16(
                    vf0[c], pf[c], o0, 0, 0, 0);
                o1 = __builtin_amdgcn_mfma_f32_32x32x16_bf16(
                    vf1[c], pf[c], o1, 0, 0, 0);
            }
            __builtin_amdgcn_s_setprio(0);
        }

        // ---- finish: combine l across lane pair, normalize, store ----
        l += __shfl_xor(l, 32);
        const float inv = 1.f / l;
        u16* Orow = O + ((long)(bb * 2048 + qw + lq)) * 1024 + h * 64;
#pragma unroll
        for (int k4 = 0; k4 < 4; ++k4) {
            u16x4 w0, w1;
#pragma unroll
            for (int j = 0; j < 4; ++j) {
                w0[j] = f2bf(o0[k4 * 4 + j] * inv);
                w1[j] = f2bf(o1[k4 * 4 + j] * inv);
            }
            *reinterpret_cast<u16x4*>(Orow + 8 * k4 + 4 * hi)      = w0;
            *reinterpret_cast<u16x4*>(Orow + 32 + 8 * k4 + 4 * hi) = w1;
        }
    }
}

// ---------------------------------------------------------------------------
// launch
// ---------------------------------------------------------------------------
extern "C" void kernel_launch(void* const* d_in, const int* in_sizes, int n_in,
                              void* d_out, int out_size, void* d_ws, size_t ws_size,
                              hipStream_t stream) {
    const float* x      = (const float*)d_in[0];
    const float* ln1_g  = (const float*)d_in[1];
    const float* ln1_b  = (const float*)d_in[2];
    const float* qkv_w  = (const float*)d_in[3];
    const float* qkv_b  = (const float*)d_in[4];
    const float* out_w  = (const float*)d_in[5];
    const float* out_b  = (const float*)d_in[6];
    const float* ln2_g  = (const float*)d_in[7];
    const float* ln2_b  = (const float*)d_in[8];
    const float* fc1_w  = (const float*)d_in[9];
    const float* fc1_b  = (const float*)d_in[10];
    const float* fc2_w  = (const float*)d_in[11];
    const float* fc2_b  = (const float*)d_in[12];
    float* out = (float*)d_out;

    const size_t MB = 1024ull * 1024ull;
    if (ws_size < 120 * MB) return;
    char* ws = (char*)d_ws;
    u16* wqkv = (u16*)(ws + 0);        // 6 MB
    u16* wout = (u16*)(ws + 6 * MB);   // 2 MB
    u16* wfc1 = (u16*)(ws + 8 * MB);   // 8 MB
    u16* wfc2 = (u16*)(ws + 16 * MB);  // 8 MB
    u16* hbuf = (u16*)(ws + 24 * MB);  // 16 MB  (LN output, bf16)
    u16* obuf = (u16*)(ws + 40 * MB);  // 16 MB  (attn output, bf16)
    u16* Qb   = (u16*)(ws + 56 * MB);  // 16 MB
    u16* Kb   = (u16*)(ws + 72 * MB);  // 16 MB
    u16* Vtb  = (u16*)(ws + 88 * MB);  // 16 MB
    u16* gbuf = (u16*)(ws + 56 * MB);  // 64 MB  (FFN hidden, reuses Q/K/Vt)

    cvt_f32_bf16<<<3072, 256, 0, stream>>>(qkv_w, wqkv, 3072 * 1024 / 4);
    cvt_f32_bf16<<<1024, 256, 0, stream>>>(out_w, wout, 1024 * 1024 / 4);
    cvt_f32_bf16<<<4096, 256, 0, stream>>>(fc1_w, wfc1, 4096 * 1024 / 4);
    cvt_f32_bf16<<<4096, 256, 0, stream>>>(fc2_w, wfc2, 1024 * 4096 / 4);

    ln_bf16<<<8192, 256, 0, stream>>>(x, ln1_g, ln1_b, hbuf);
    // QKV: 64 x 24 = 1536 blocks
    gemm_bt<3><<<dim3(1536), 256, 0, stream>>>(hbuf, wqkv, qkv_b, nullptr,
                                               nullptr, nullptr, Qb, Kb, Vtb,
                                               8192, 3072, 1024);
    attn_fwd32<<<dim3(64, 8), 256, 0, stream>>>(Qb, Kb, Vtb, obuf);
    // out-proj: 64 x 8 = 512 blocks
    gemm_bt<2><<<dim3(512), 256, 0, stream>>>(obuf, wout, out_b, x, out,
                                              nullptr, nullptr, nullptr, nullptr,
                                              8192, 1024, 1024);
    ln_bf16<<<8192, 256, 0, stream>>>(out, ln2_g, ln2_b, hbuf);
    // FC1: 64 x 32 = 2048 blocks
    gemm_bt<1><<<dim3(2048), 256, 0, stream>>>(hbuf, wfc1, fc1_b, nullptr,
                                               nullptr, gbuf, nullptr, nullptr,
                                               nullptr, 8192, 4096, 1024);
    // FC2: 64 x 8 = 512 blocks
    gemm_bt<2><<<dim3(512), 256, 0, stream>>>(gbuf, wfc2, fc2_b, out, out,
                                              nullptr, nullptr, nullptr, nullptr,
                                              8192, 1024, 4096);
}

// Round 7
// 447.175 us; speedup vs baseline: 1.3036x; 1.0125x over previous
//
#include <hip/hip_runtime.h>
#include <math.h>

// ---------------------------------------------------------------------------
// Types / helpers
// ---------------------------------------------------------------------------
using u16 = unsigned short;
typedef __attribute__((ext_vector_type(8))) short short8;   // 8 x bf16 (raw bits)
typedef __attribute__((ext_vector_type(4))) float f32x4;
typedef __attribute__((ext_vector_type(16))) float f32x16;
typedef __attribute__((ext_vector_type(4))) u16 u16x4;

#define DEV __device__ __forceinline__

DEV u16 f2bf(float f) {                       // f32 -> bf16, round-nearest-even
    unsigned u = __float_as_uint(f);
    u += 0x7fffu + ((u >> 16) & 1u);
    return (u16)(u >> 16);
}
DEV float bf2f(u16 h) { return __uint_as_float(((unsigned)h) << 16); }

DEV short8 ld16(const u16* p) { return *reinterpret_cast<const short8*>(p); }

DEV float gelu_f(float x) { return 0.5f * x * (1.f + erff(x * 0.70710678118654752f)); }

DEV unsigned pk2(float a, float b) {          // packed bf16x2 via HW cvt (RNE)
    unsigned r;
    asm("v_cvt_pk_bf16_f32 %0, %1, %2" : "=v"(r) : "v"(a), "v"(b));
    return r;
}

// async global->LDS, 16B per lane, LDS dest = wave-uniform base + lane*16
#define GLL16(gp, lp)                                                          \
    __builtin_amdgcn_global_load_lds(                                          \
        (const __attribute__((address_space(1))) void*)(gp),                   \
        (__attribute__((address_space(3))) void*)(lp), 16, 0, 0)

// ---------------------------------------------------------------------------
// fp32 -> bf16 convert (weights)
// ---------------------------------------------------------------------------
__global__ void cvt_f32_bf16(const float* __restrict__ in, u16* __restrict__ out, int n4) {
    int i = blockIdx.x * 256 + threadIdx.x;
    if (i >= n4) return;
    float4 v = reinterpret_cast<const float4*>(in)[i];
    u16x4 o;
    o.x = f2bf(v.x); o.y = f2bf(v.y); o.z = f2bf(v.z); o.w = f2bf(v.w);
    reinterpret_cast<u16x4*>(out)[i] = o;
}

// ---------------------------------------------------------------------------
// LayerNorm (fp32 in) -> bf16 out.  One block per row, 256 threads x 4 floats.
// ---------------------------------------------------------------------------
__global__ __launch_bounds__(256) void ln_bf16(const float* __restrict__ x,
                                               const float* __restrict__ gm,
                                               const float* __restrict__ bt,
                                               u16* __restrict__ out) {
    const int row = blockIdx.x, tid = threadIdx.x;
    const float4 v = reinterpret_cast<const float4*>(x + (long)row * 1024)[tid];
    float s  = v.x + v.y + v.z + v.w;
    float sq = v.x * v.x + v.y * v.y + v.z * v.z + v.w * v.w;
#pragma unroll
    for (int off = 1; off <= 32; off <<= 1) {
        s  += __shfl_xor(s, off);
        sq += __shfl_xor(sq, off);
    }
    __shared__ float ss[4], ssq[4];
    const int wave = tid >> 6, lane = tid & 63;
    if (lane == 0) { ss[wave] = s; ssq[wave] = sq; }
    __syncthreads();
    s  = ss[0] + ss[1] + ss[2] + ss[3];
    sq = ssq[0] + ssq[1] + ssq[2] + ssq[3];
    const float mu   = s * (1.f / 1024.f);
    const float var  = sq * (1.f / 1024.f) - mu * mu;
    const float rstd = rsqrtf(var + 1e-5f);
    const float4 g4 = reinterpret_cast<const float4*>(gm)[tid];
    const float4 b4 = reinterpret_cast<const float4*>(bt)[tid];
    u16x4 o;
    o.x = f2bf((v.x - mu) * rstd * g4.x + b4.x);
    o.y = f2bf((v.y - mu) * rstd * g4.y + b4.y);
    o.z = f2bf((v.z - mu) * rstd * g4.z + b4.z);
    o.w = f2bf((v.w - mu) * rstd * g4.w + b4.w);
    reinterpret_cast<u16x4*>(out + (long)row * 1024)[tid] = o;
}

// ---------------------------------------------------------------------------
// m97-style GEMM + 2-phase prefetch: C[M,N] = A[M,K] @ B[N,K]^T + bias.
// 128x128 tile, BK=32, 4 waves (2x2), double-buffered LDS (2 x 16KB):
// STAGE(next tile) issued BEFORE ds_read+MFMA of current; the single
// end-of-iter barrier drains vmcnt -> staging latency hides under compute.
// XOR-swizzled LDS (pre-swizzled source + swizzled ds_read; 0 conflicts).
// MFMA (bfr, af) order -> row-major D frag -> vectorized epilogue stores.
// EPI: 0 = bf16 out, 1 = bf16 gelu out, 2 = fp32 out + residual,
//      3 = QKV: Q (pre-scaled by 1/sqrt(64)*log2e) / K direct; V via
//          in-LDS 128x128 transpose -> Vt (reuses the staging pool).
// ---------------------------------------------------------------------------
#define TS(c, r) ((c) * 128 + (((((r) >> 3) ^ ((c) & 15))) << 3) + ((r) & 7))

template <int EPI>
__global__ __launch_bounds__(256, 3) void gemm_bt(
    const u16* __restrict__ A, const u16* __restrict__ B,
    const float* __restrict__ bias, const float* res, float* outf,
    u16* __restrict__ outb, u16* __restrict__ Qb, u16* __restrict__ Kb,
    u16* __restrict__ Vtb, int M, int N, int K) {
    __shared__ u16 shpool[16384];   // 2 bufs x (A 128x32 + B 128x32); also Vt transpose

    const int tid = threadIdx.x;
    const int wave = tid >> 6, lane = tid & 63;
    const int lo = lane & 15, g = lane >> 4;
    const int wr = wave >> 1, wc = wave & 1;

    // XCD-chunked bijective swizzle; bn fastest (co-resident blocks share A)
    const int nwg = gridDim.x, chunk = nwg >> 3;
    const int wgid = (blockIdx.x & 7) * chunk + (blockIdx.x >> 3);
    const int NB = N >> 7;
    const int bm = wgid / NB, bn = wgid % NB;
    const int row0 = bm * 128, col0 = bn * 128;

    // staging source (pre-swizzled logical chunk so linear LDS dest = swizzled)
    const int lrow = lane >> 2;
    const int lg   = (lane & 3) ^ ((lane >> 3) & 3);
    const u16* Ag = A + (long)(row0 + wave * 16 + lrow) * K + lg * 8;
    const u16* Bg = B + (long)(col0 + wave * 16 + lrow) * K + lg * 8;

#define STAGE(tb, kt) do {                                                     \
        u16* Al = shpool + (tb) * 8192 + wave * 512;                           \
        u16* Bl = Al + 4096;                                                   \
        GLL16(Ag + (long)(kt) * 32, Al);                                       \
        GLL16(Ag + 64 * (long)K + (long)(kt) * 32, Al + 2048);                 \
        GLL16(Bg + (long)(kt) * 32, Bl);                                       \
        GLL16(Bg + 64 * (long)K + (long)(kt) * 32, Bl + 2048);                 \
    } while (0)

    const int agp = g ^ ((lo >> 1) & 3);      // swizzled ds_read chunk
    f32x4 acc[4][4] = {};

    STAGE(0, 0);
    __syncthreads();                          // prologue drain: tile 0 landed

    const int T = K >> 5;
    for (int t = 0; t < T; ++t) {
        const int cur = t & 1;
        if (t + 1 < T) STAGE(cur ^ 1, t + 1);          // prefetch next tile
        const u16* As = shpool + cur * 8192;
        const u16* Bs = As + 4096;
        short8 af[4], bfr[4];
#pragma unroll
        for (int m = 0; m < 4; ++m)
            af[m] = ld16(&As[(wr * 64 + m * 16 + lo) * 32 + agp * 8]);
#pragma unroll
        for (int n = 0; n < 4; ++n)
            bfr[n] = ld16(&Bs[(wc * 64 + n * 16 + lo) * 32 + agp * 8]);
#pragma unroll
        for (int m = 0; m < 4; ++m)
#pragma unroll
            for (int n = 0; n < 4; ++n)
                acc[m][n] = __builtin_amdgcn_mfma_f32_16x16x32_bf16(
                    bfr[n], af[m], acc[m][n], 0, 0, 0);
        __syncthreads();   // drains vmcnt (prefetch landed) + all reads done
    }
#undef STAGE

    // ---- epilogue: row-major frags: row = ...+lo, 4 consecutive cols ----
    if constexpr (EPI == 3) {
        if (col0 >= 2048) {       // V block: transpose via LDS, coalesced Vt
#pragma unroll
            for (int n = 0; n < 4; ++n) {
                const int cb = wc * 64 + n * 16 + g * 4;
                const float4 b4 = *reinterpret_cast<const float4*>(&bias[col0 + cb]);
#pragma unroll
                for (int m = 0; m < 4; ++m) {
                    const int rl = wr * 64 + m * 16 + lo;
                    shpool[TS(cb + 0, rl)] = f2bf(acc[m][n][0] + b4.x);
                    shpool[TS(cb + 1, rl)] = f2bf(acc[m][n][1] + b4.y);
                    shpool[TS(cb + 2, rl)] = f2bf(acc[m][n][2] + b4.z);
                    shpool[TS(cb + 3, rl)] = f2bf(acc[m][n][3] + b4.w);
                }
            }
            __syncthreads();
            const int c = tid >> 1, half = tid & 1;
            const int dcol = (col0 - 2048) + c;
            const int head = dcol >> 6, d = dcol & 63;
            const int bb = row0 >> 11;
            u16* dst = Vtb + ((long)(bb * 16 + head) * 64 + d) * 2048 +
                       (row0 & 2047) + half * 64;
            const u16* srcb = shpool + c * 128;
#pragma unroll
            for (int i = 0; i < 8; ++i) {
                const int pc = (half * 8 + i) ^ (c & 15);
                *reinterpret_cast<short8*>(dst + i * 8) =
                    *reinterpret_cast<const short8*>(srcb + pc * 8);
            }
            return;
        }
    }
#pragma unroll
    for (int n = 0; n < 4; ++n) {
        const int cb = col0 + wc * 64 + n * 16 + g * 4;
        const float4 b4 = *reinterpret_cast<const float4*>(&bias[cb]);
#pragma unroll
        for (int m = 0; m < 4; ++m) {
            const int r = row0 + wr * 64 + m * 16 + lo;
            const float v0 = acc[m][n][0] + b4.x;
            const float v1 = acc[m][n][1] + b4.y;
            const float v2 = acc[m][n][2] + b4.z;
            const float v3 = acc[m][n][3] + b4.w;
            if constexpr (EPI == 0) {
                u16x4 o = {f2bf(v0), f2bf(v1), f2bf(v2), f2bf(v3)};
                *reinterpret_cast<u16x4*>(&outb[(long)r * N + cb]) = o;
            } else if constexpr (EPI == 1) {
                u16x4 o = {f2bf(gelu_f(v0)), f2bf(gelu_f(v1)),
                           f2bf(gelu_f(v2)), f2bf(gelu_f(v3))};
                *reinterpret_cast<u16x4*>(&outb[(long)r * N + cb]) = o;
            } else if constexpr (EPI == 2) {
                const float4 rr = *reinterpret_cast<const float4*>(&res[(long)r * N + cb]);
                float4 o = {rr.x + v0, rr.y + v1, rr.z + v2, rr.w + v3};
                *reinterpret_cast<float4*>(&outf[(long)r * N + cb]) = o;
            } else {  // EPI == 3, Q/K block
                const int part = cb >> 10, cc = cb & 1023;
                const int head = cc >> 6, d = cc & 63;
                const int bb = r >> 11, srow = r & 2047;
                const int bh = bb * 16 + head;
                // Q pre-scaled into log2 domain for exp2 softmax
                const float qs = (part == 0) ? 0.18033688f : 1.0f;
                u16x4 o = {f2bf(v0 * qs), f2bf(v1 * qs), f2bf(v2 * qs), f2bf(v3 * qs)};
                u16* base = (part == 0) ? Qb : Kb;
                *reinterpret_cast<u16x4*>(&base[((long)bh * 2048 + srow) * 64 + d]) = o;
            }
        }
    }
}

// ---------------------------------------------------------------------------
// Causal flash attention, 32x32x16 MFMA.  One block per 128-row q-strip
// (grid 64 x 16, heavy strips first) -> up to 16 waves/CU.  Q pre-scaled by
// 1/sqrt(64)*log2e -> softmax in exp2 domain (1 sub + 1 v_exp_f32 per elem).
// V prefetch before softmax; defer-max (THR=11.5 log2); setprio on MFMA.
// ---------------------------------------------------------------------------
__global__ __launch_bounds__(256) void attn_fwd32(
    const u16* __restrict__ Q, const u16* __restrict__ K,
    const u16* __restrict__ Vt, u16* __restrict__ O) {
    const int bh = blockIdx.x;
    const int qt = 15 - blockIdx.y;          // heavy strips dispatch first
    const int wave = threadIdx.x >> 6, lane = threadIdx.x & 63;
    const int lq = lane & 31, hi = lane >> 5;
    const int qw = qt * 128 + wave * 32;

    const u16* Kp = K + (long)bh * 2048 * 64;
    const u16* Vp = Vt + (long)bh * 64 * 2048;
    const int bb = bh >> 4, h = bh & 15;
    const u16* Qp = Q + ((long)bh * 2048 + qw) * 64;

    short8 qf[4];
#pragma unroll
    for (int ks = 0; ks < 4; ++ks)
        qf[ks] = ld16(Qp + lq * 64 + ks * 16 + hi * 8);

    f32x16 o0 = {}, o1 = {};
    float m = -1e30f, l = 0.f;
    const int q_abs = qw + lq;
    const int nkv = qw + 32;

    for (int kv0 = 0; kv0 < nkv; kv0 += 64) {
        // ---- S^T = K * Q^T  (two 32-kv tiles), log2 domain ----
        f32x16 s0 = {}, s1 = {};
        const u16* Kr = Kp + (long)(kv0 + lq) * 64 + hi * 8;
        __builtin_amdgcn_s_setprio(1);
#pragma unroll
        for (int ks = 0; ks < 4; ++ks)
            s0 = __builtin_amdgcn_mfma_f32_32x32x16_bf16(
                ld16(Kr + ks * 16), qf[ks], s0, 0, 0, 0);
        const u16* Kr2 = Kr + 32 * 64;
#pragma unroll
        for (int ks = 0; ks < 4; ++ks)
            s1 = __builtin_amdgcn_mfma_f32_32x32x16_bf16(
                ld16(Kr2 + ks * 16), qf[ks], s1, 0, 0, 0);
        __builtin_amdgcn_s_setprio(0);

        // ---- V prefetch (latency hides under softmax below) ----
        const u16* Vr = Vp + (long)lq * 2048 + kv0 + hi * 8;
        short8 vf0[4], vf1[4];
#pragma unroll
        for (int c = 0; c < 4; ++c) {
            vf0[c] = ld16(Vr + c * 16);
            vf1[c] = ld16(Vr + 32 * 2048 + c * 16);
        }

        // ---- causal mask (diagonal tile only) + row max ----
        float mt = -1e30f;
        if (kv0 + 64 >= nkv) {               // diagonal tile
#pragma unroll
            for (int r = 0; r < 16; ++r) {
                const int kv = kv0 + (r & 3) + 8 * (r >> 2) + 4 * hi;
                if (kv > q_abs) s0[r] = -1e30f;
                mt = fmaxf(mt, s0[r]);
                if (kv + 32 > q_abs) s1[r] = -1e30f;
                mt = fmaxf(mt, s1[r]);
            }
        } else {
#pragma unroll
            for (int r = 0; r < 16; ++r)
                mt = fmaxf(mt, fmaxf(s0[r], s1[r]));
        }
        mt = fmaxf(mt, __shfl_xor(mt, 32));

        // ---- defer-max: rescale only when max grew past threshold ----
        if (!__all(mt <= m + 11.5f)) {
            const float mn = fmaxf(m, mt);
            const float corr = __builtin_amdgcn_exp2f(m - mn);
            m = mn;
            l *= corr;
            o0 *= corr; o1 *= corr;
        }
        float ps = 0.f;
#pragma unroll
        for (int r = 0; r < 16; ++r) {
            s0[r] = __builtin_amdgcn_exp2f(s0[r] - m); ps += s0[r];
            s1[r] = __builtin_amdgcn_exp2f(s1[r] - m); ps += s1[r];
        }
        l += ps;

        // ---- build P^T B-frags (4 chunks of kv16), 2 shuffles each ----
        short8 pf[4];
#pragma unroll
        for (int c = 0; c < 4; ++c) {
            const f32x16& src = (c >> 1) ? s1 : s0;
            const int b = (c & 1) * 8;
            const unsigned A0 = pk2(src[b + 0], src[b + 1]);
            const unsigned A1 = pk2(src[b + 2], src[b + 3]);
            const unsigned B0 = pk2(src[b + 4], src[b + 5]);
            const unsigned B1 = pk2(src[b + 6], src[b + 7]);
            const unsigned S0 = hi ? A0 : B0;
            const unsigned S1 = hi ? A1 : B1;
            const unsigned R0 = (unsigned)__shfl_xor((int)S0, 32);
            const unsigned R1 = (unsigned)__shfl_xor((int)S1, 32);
            union { unsigned u[4]; short8 v; } fr;
            fr.u[0] = hi ? R0 : A0;
            fr.u[1] = hi ? R1 : A1;
            fr.u[2] = hi ? B0 : R0;
            fr.u[3] = hi ? B1 : R1;
            pf[c] = fr.v;
        }

        // ---- O^T += Vt * P^T ----
        __builtin_amdgcn_s_setprio(1);
#pragma unroll
        for (int c = 0; c < 4; ++c) {
            o0 = __builtin_amdgcn_mfma_f32_32x32x16_bf16(
                vf0[c], pf[c], o0, 0, 0, 0);
            o1 = __builtin_amdgcn_mfma_f32_32x32x16_bf16(
                vf1[c], pf[c], o1, 0, 0, 0);
        }
        __builtin_amdgcn_s_setprio(0);
    }

    // ---- finish: combine l across lane pair, normalize, store ----
    l += __shfl_xor(l, 32);
    const float inv = 1.f / l;
    u16* Orow = O + ((long)(bb * 2048 + qw + lq)) * 1024 + h * 64;
#pragma unroll
    for (int k4 = 0; k4 < 4; ++k4) {
        u16x4 w0, w1;
#pragma unroll
        for (int j = 0; j < 4; ++j) {
            w0[j] = f2bf(o0[k4 * 4 + j] * inv);
            w1[j] = f2bf(o1[k4 * 4 + j] * inv);
        }
        *reinterpret_cast<u16x4*>(Orow + 8 * k4 + 4 * hi)      = w0;
        *reinterpret_cast<u16x4*>(Orow + 32 + 8 * k4 + 4 * hi) = w1;
    }
}

// ---------------------------------------------------------------------------
// launch
// ---------------------------------------------------------------------------
extern "C" void kernel_launch(void* const* d_in, const int* in_sizes, int n_in,
                              void* d_out, int out_size, void* d_ws, size_t ws_size,
                              hipStream_t stream) {
    const float* x      = (const float*)d_in[0];
    const float* ln1_g  = (const float*)d_in[1];
    const float* ln1_b  = (const float*)d_in[2];
    const float* qkv_w  = (const float*)d_in[3];
    const float* qkv_b  = (const float*)d_in[4];
    const float* out_w  = (const float*)d_in[5];
    const float* out_b  = (const float*)d_in[6];
    const float* ln2_g  = (const float*)d_in[7];
    const float* ln2_b  = (const float*)d_in[8];
    const float* fc1_w  = (const float*)d_in[9];
    const float* fc1_b  = (const float*)d_in[10];
    const float* fc2_w  = (const float*)d_in[11];
    const float* fc2_b  = (const float*)d_in[12];
    float* out = (float*)d_out;

    const size_t MB = 1024ull * 1024ull;
    if (ws_size < 120 * MB) return;
    char* ws = (char*)d_ws;
    u16* wqkv = (u16*)(ws + 0);        // 6 MB
    u16* wout = (u16*)(ws + 6 * MB);   // 2 MB
    u16* wfc1 = (u16*)(ws + 8 * MB);   // 8 MB
    u16* wfc2 = (u16*)(ws + 16 * MB);  // 8 MB
    u16* hbuf = (u16*)(ws + 24 * MB);  // 16 MB  (LN output, bf16)
    u16* obuf = (u16*)(ws + 40 * MB);  // 16 MB  (attn output, bf16)
    u16* Qb   = (u16*)(ws + 56 * MB);  // 16 MB
    u16* Kb   = (u16*)(ws + 72 * MB);  // 16 MB
    u16* Vtb  = (u16*)(ws + 88 * MB);  // 16 MB
    u16* gbuf = (u16*)(ws + 56 * MB);  // 64 MB  (FFN hidden, reuses Q/K/Vt)

    cvt_f32_bf16<<<3072, 256, 0, stream>>>(qkv_w, wqkv, 3072 * 1024 / 4);
    cvt_f32_bf16<<<1024, 256, 0, stream>>>(out_w, wout, 1024 * 1024 / 4);
    cvt_f32_bf16<<<4096, 256, 0, stream>>>(fc1_w, wfc1, 4096 * 1024 / 4);
    cvt_f32_bf16<<<4096, 256, 0, stream>>>(fc2_w, wfc2, 1024 * 4096 / 4);

    ln_bf16<<<8192, 256, 0, stream>>>(x, ln1_g, ln1_b, hbuf);
    // QKV: 64 x 24 = 1536 blocks
    gemm_bt<3><<<dim3(1536), 256, 0, stream>>>(hbuf, wqkv, qkv_b, nullptr,
                                               nullptr, nullptr, Qb, Kb, Vtb,
                                               8192, 3072, 1024);
    attn_fwd32<<<dim3(64, 16), 256, 0, stream>>>(Qb, Kb, Vtb, obuf);
    // out-proj: 64 x 8 = 512 blocks
    gemm_bt<2><<<dim3(512), 256, 0, stream>>>(obuf, wout, out_b, x, out,
                                              nullptr, nullptr, nullptr, nullptr,
                                              8192, 1024, 1024);
    ln_bf16<<<8192, 256, 0, stream>>>(out, ln2_g, ln2_b, hbuf);
    // FC1: 64 x 32 = 2048 blocks
    gemm_bt<1><<<dim3(2048), 256, 0, stream>>>(hbuf, wfc1, fc1_b, nullptr,
                                               nullptr, gbuf, nullptr, nullptr,
                                               nullptr, 8192, 4096, 1024);
    // FC2: 64 x 8 = 512 blocks
    gemm_bt<2><<<dim3(512), 256, 0, stream>>>(gbuf, wfc2, fc2_b, out, out,
                                              nullptr, nullptr, nullptr, nullptr,
                                              8192, 1024, 4096);
}

// Round 8
// 445.760 us; speedup vs baseline: 1.3078x; 1.0032x over previous
//
#include <hip/hip_runtime.h>
#include <math.h>

// ---------------------------------------------------------------------------
// Types / helpers
// ---------------------------------------------------------------------------
using u16 = unsigned short;
typedef __attribute__((ext_vector_type(8))) short short8;   // 8 x bf16 (raw bits)
typedef __attribute__((ext_vector_type(4))) float f32x4;
typedef __attribute__((ext_vector_type(16))) float f32x16;
typedef __attribute__((ext_vector_type(4))) u16 u16x4;

#define DEV __device__ __forceinline__

DEV u16 f2bf(float f) {                       // f32 -> bf16, round-nearest-even
    unsigned u = __float_as_uint(f);
    u += 0x7fffu + ((u >> 16) & 1u);
    return (u16)(u >> 16);
}
DEV float bf2f(u16 h) { return __uint_as_float(((unsigned)h) << 16); }

DEV short8 ld16(const u16* p) { return *reinterpret_cast<const short8*>(p); }

DEV float gelu_f(float x) { return 0.5f * x * (1.f + erff(x * 0.70710678118654752f)); }

DEV unsigned pk2(float a, float b) {          // packed bf16x2 via HW cvt (RNE)
    unsigned r;
    asm("v_cvt_pk_bf16_f32 %0, %1, %2" : "=v"(r) : "v"(a), "v"(b));
    return r;
}

// async global->LDS, 16B per lane, LDS dest = wave-uniform base + lane*16
#define GLL16(gp, lp)                                                          \
    __builtin_amdgcn_global_load_lds(                                          \
        (const __attribute__((address_space(1))) void*)(gp),                   \
        (__attribute__((address_space(3))) void*)(lp), 16, 0, 0)

#define VMC(n) asm volatile("s_waitcnt vmcnt(" #n ")" ::: "memory")
#define LGKM0() asm volatile("s_waitcnt lgkmcnt(0)" ::: "memory")

// ---------------------------------------------------------------------------
// fp32 -> bf16 convert (weights)
// ---------------------------------------------------------------------------
__global__ void cvt_f32_bf16(const float* __restrict__ in, u16* __restrict__ out, int n4) {
    int i = blockIdx.x * 256 + threadIdx.x;
    if (i >= n4) return;
    float4 v = reinterpret_cast<const float4*>(in)[i];
    u16x4 o;
    o.x = f2bf(v.x); o.y = f2bf(v.y); o.z = f2bf(v.z); o.w = f2bf(v.w);
    reinterpret_cast<u16x4*>(out)[i] = o;
}

// ---------------------------------------------------------------------------
// LayerNorm (fp32 in) -> bf16 out.  One block per row, 256 threads x 4 floats.
// ---------------------------------------------------------------------------
__global__ __launch_bounds__(256) void ln_bf16(const float* __restrict__ x,
                                               const float* __restrict__ gm,
                                               const float* __restrict__ bt,
                                               u16* __restrict__ out) {
    const int row = blockIdx.x, tid = threadIdx.x;
    const float4 v = reinterpret_cast<const float4*>(x + (long)row * 1024)[tid];
    float s  = v.x + v.y + v.z + v.w;
    float sq = v.x * v.x + v.y * v.y + v.z * v.z + v.w * v.w;
#pragma unroll
    for (int off = 1; off <= 32; off <<= 1) {
        s  += __shfl_xor(s, off);
        sq += __shfl_xor(sq, off);
    }
    __shared__ float ss[4], ssq[4];
    const int wave = tid >> 6, lane = tid & 63;
    if (lane == 0) { ss[wave] = s; ssq[wave] = sq; }
    __syncthreads();
    s  = ss[0] + ss[1] + ss[2] + ss[3];
    sq = ssq[0] + ssq[1] + ssq[2] + ssq[3];
    const float mu   = s * (1.f / 1024.f);
    const float var  = sq * (1.f / 1024.f) - mu * mu;
    const float rstd = rsqrtf(var + 1e-5f);
    const float4 g4 = reinterpret_cast<const float4*>(gm)[tid];
    const float4 b4 = reinterpret_cast<const float4*>(bt)[tid];
    u16x4 o;
    o.x = f2bf((v.x - mu) * rstd * g4.x + b4.x);
    o.y = f2bf((v.y - mu) * rstd * g4.y + b4.y);
    o.z = f2bf((v.z - mu) * rstd * g4.z + b4.z);
    o.w = f2bf((v.w - mu) * rstd * g4.w + b4.w);
    reinterpret_cast<u16x4*>(out + (long)row * 1024)[tid] = o;
}

// ---------------------------------------------------------------------------
// m97-style GEMM + counted-vmcnt 2-ahead pipeline (T3+T4 minimum form):
// C[M,N] = A[M,K] @ B[N,K]^T + bias.  128x128 tile, BK=32, 4 waves (2x2),
// 2 LDS buffers (32 KB).  Tile t's loads issued at iter t-2; per iter:
//   VMC(4) -> s_barrier            (tile t landed, everywhere)
//   ds_read frags; lgkmcnt(0)      (reads drained -- WAR fence)
//   s_barrier                      (ALL waves' reads done)
//   STAGE(t+2) into buf just read  (safe overwrite)
//   16 MFMA                        (covers in-flight loads)
// XOR-swizzled LDS (pre-swizzled source + swizzled ds_read; 0 conflicts).
// MFMA (bfr, af) order -> row-major D frag -> vectorized epilogue stores.
// EPI: 0 = bf16 out, 1 = bf16 gelu out, 2 = fp32 out + residual,
//      3 = QKV: Q (pre-scaled by 1/sqrt(64)*log2e) / K direct; V via
//          in-LDS 128x128 transpose -> Vt (reuses the staging pool).
// ---------------------------------------------------------------------------
#define TS(c, r) ((c) * 128 + (((((r) >> 3) ^ ((c) & 15))) << 3) + ((r) & 7))

template <int EPI>
__global__ __launch_bounds__(256, 3) void gemm_bt(
    const u16* __restrict__ A, const u16* __restrict__ B,
    const float* __restrict__ bias, const float* res, float* outf,
    u16* __restrict__ outb, u16* __restrict__ Qb, u16* __restrict__ Kb,
    u16* __restrict__ Vtb, int M, int N, int K) {
    __shared__ u16 shpool[16384];   // 2 bufs x (A 128x32 + B 128x32); also Vt transpose

    const int tid = threadIdx.x;
    const int wave = tid >> 6, lane = tid & 63;
    const int lo = lane & 15, g = lane >> 4;
    const int wr = wave >> 1, wc = wave & 1;

    // XCD-chunked bijective swizzle; bn fastest (co-resident blocks share A)
    const int nwg = gridDim.x, chunk = nwg >> 3;
    const int wgid = (blockIdx.x & 7) * chunk + (blockIdx.x >> 3);
    const int NB = N >> 7;
    const int bm = wgid / NB, bn = wgid % NB;
    const int row0 = bm * 128, col0 = bn * 128;

    // staging source (pre-swizzled logical chunk so linear LDS dest = swizzled)
    const int lrow = lane >> 2;
    const int lg   = (lane & 3) ^ ((lane >> 3) & 3);
    const u16* Ag = A + (long)(row0 + wave * 16 + lrow) * K + lg * 8;
    const u16* Bg = B + (long)(col0 + wave * 16 + lrow) * K + lg * 8;

#define STAGE(tb, kt) do {                                                     \
        u16* Al = shpool + (tb) * 8192 + wave * 512;                           \
        u16* Bl = Al + 4096;                                                   \
        GLL16(Ag + (long)(kt) * 32, Al);                                       \
        GLL16(Ag + 64 * (long)K + (long)(kt) * 32, Al + 2048);                 \
        GLL16(Bg + (long)(kt) * 32, Bl);                                       \
        GLL16(Bg + 64 * (long)K + (long)(kt) * 32, Bl + 2048);                 \
    } while (0)

    const int agp = g ^ ((lo >> 1) & 3);      // swizzled ds_read chunk
    f32x4 acc[4][4] = {};

    STAGE(0, 0);
    STAGE(1, 1);

    const int T = K >> 5;
    for (int t = 0; t < T; ++t) {
        const int cur = t & 1;
        if (t + 2 < T) { VMC(4); } else { VMC(0); }
        __builtin_amdgcn_s_barrier();         // tile t visible to all waves
        const u16* As = shpool + cur * 8192;
        const u16* Bs = As + 4096;
        short8 af[4], bfr[4];
#pragma unroll
        for (int m = 0; m < 4; ++m)
            af[m] = ld16(&As[(wr * 64 + m * 16 + lo) * 32 + agp * 8]);
#pragma unroll
        for (int n = 0; n < 4; ++n)
            bfr[n] = ld16(&Bs[(wc * 64 + n * 16 + lo) * 32 + agp * 8]);
        LGKM0();                              // own reads drained (WAR fence)
        __builtin_amdgcn_s_barrier();         // all waves' reads done
        if (t + 2 < T) STAGE(cur, t + 2);     // safe overwrite; flies under MFMA
#pragma unroll
        for (int m = 0; m < 4; ++m)
#pragma unroll
            for (int n = 0; n < 4; ++n)
                acc[m][n] = __builtin_amdgcn_mfma_f32_16x16x32_bf16(
                    bfr[n], af[m], acc[m][n], 0, 0, 0);
    }
#undef STAGE

    // ---- epilogue: row-major frags: row = ...+lo, 4 consecutive cols ----
    if constexpr (EPI == 3) {
        if (col0 >= 2048) {       // V block: transpose via LDS, coalesced Vt
            __syncthreads();      // all waves out of the K-loop (LDS reuse)
#pragma unroll
            for (int n = 0; n < 4; ++n) {
                const int cb = wc * 64 + n * 16 + g * 4;
                const float4 b4 = *reinterpret_cast<const float4*>(&bias[col0 + cb]);
#pragma unroll
                for (int m = 0; m < 4; ++m) {
                    const int rl = wr * 64 + m * 16 + lo;
                    shpool[TS(cb + 0, rl)] = f2bf(acc[m][n][0] + b4.x);
                    shpool[TS(cb + 1, rl)] = f2bf(acc[m][n][1] + b4.y);
                    shpool[TS(cb + 2, rl)] = f2bf(acc[m][n][2] + b4.z);
                    shpool[TS(cb + 3, rl)] = f2bf(acc[m][n][3] + b4.w);
                }
            }
            __syncthreads();
            const int c = tid >> 1, half = tid & 1;
            const int dcol = (col0 - 2048) + c;
            const int head = dcol >> 6, d = dcol & 63;
            const int bb = row0 >> 11;
            u16* dst = Vtb + ((long)(bb * 16 + head) * 64 + d) * 2048 +
                       (row0 & 2047) + half * 64;
            const u16* srcb = shpool + c * 128;
#pragma unroll
            for (int i = 0; i < 8; ++i) {
                const int pc = (half * 8 + i) ^ (c & 15);
                *reinterpret_cast<short8*>(dst + i * 8) =
                    *reinterpret_cast<const short8*>(srcb + pc * 8);
            }
            return;
        }
    }
#pragma unroll
    for (int n = 0; n < 4; ++n) {
        const int cb = col0 + wc * 64 + n * 16 + g * 4;
        const float4 b4 = *reinterpret_cast<const float4*>(&bias[cb]);
#pragma unroll
        for (int m = 0; m < 4; ++m) {
            const int r = row0 + wr * 64 + m * 16 + lo;
            const float v0 = acc[m][n][0] + b4.x;
            const float v1 = acc[m][n][1] + b4.y;
            const float v2 = acc[m][n][2] + b4.z;
            const float v3 = acc[m][n][3] + b4.w;
            if constexpr (EPI == 0) {
                u16x4 o = {f2bf(v0), f2bf(v1), f2bf(v2), f2bf(v3)};
                *reinterpret_cast<u16x4*>(&outb[(long)r * N + cb]) = o;
            } else if constexpr (EPI == 1) {
                u16x4 o = {f2bf(gelu_f(v0)), f2bf(gelu_f(v1)),
                           f2bf(gelu_f(v2)), f2bf(gelu_f(v3))};
                *reinterpret_cast<u16x4*>(&outb[(long)r * N + cb]) = o;
            } else if constexpr (EPI == 2) {
                const float4 rr = *reinterpret_cast<const float4*>(&res[(long)r * N + cb]);
                float4 o = {rr.x + v0, rr.y + v1, rr.z + v2, rr.w + v3};
                *reinterpret_cast<float4*>(&outf[(long)r * N + cb]) = o;
            } else {  // EPI == 3, Q/K block
                const int part = cb >> 10, cc = cb & 1023;
                const int head = cc >> 6, d = cc & 63;
                const int bb = r >> 11, srow = r & 2047;
                const int bh = bb * 16 + head;
                // Q pre-scaled into log2 domain for exp2 softmax
                const float qs = (part == 0) ? 0.18033688f : 1.0f;
                u16x4 o = {f2bf(v0 * qs), f2bf(v1 * qs), f2bf(v2 * qs), f2bf(v3 * qs)};
                u16* base = (part == 0) ? Qb : Kb;
                *reinterpret_cast<u16x4*>(&base[((long)bh * 2048 + srow) * 64 + d]) = o;
            }
        }
    }
}

// ---------------------------------------------------------------------------
// Causal flash attention, 32x32x16 MFMA.  4096 equal-weight wave-jobs:
// job = 32-row q-tile of one (b,h); jobs sorted heavy-first; 4 consecutive
// jobs per 256-thread block (intra-block trips nearly equal) -> high
// occupancy, fine-grained tail.  exp2-domain softmax (Q pre-scaled);
// V prefetch before softmax; defer-max; setprio on MFMA clusters.
// ---------------------------------------------------------------------------
__global__ __launch_bounds__(256) void attn_fwd32(
    const u16* __restrict__ Q, const u16* __restrict__ K,
    const u16* __restrict__ Vt, u16* __restrict__ O) {
    const int wave = threadIdx.x >> 6, lane = threadIdx.x & 63;
    const int job = blockIdx.x * 4 + wave;   // 0..4095, heavy first
    const int qt = 63 - (job >> 6);          // q-tile index 63..0
    const int bh = job & 63;
    const int lq = lane & 31, hi = lane >> 5;
    const int qw = qt * 32;

    const u16* Kp = K + (long)bh * 2048 * 64;
    const u16* Vp = Vt + (long)bh * 64 * 2048;
    const int bb = bh >> 4, h = bh & 15;
    const u16* Qp = Q + ((long)bh * 2048 + qw) * 64;

    short8 qf[4];
#pragma unroll
    for (int ks = 0; ks < 4; ++ks)
        qf[ks] = ld16(Qp + lq * 64 + ks * 16 + hi * 8);

    f32x16 o0 = {}, o1 = {};
    float m = -1e30f, l = 0.f;
    const int q_abs = qw + lq;
    const int nkv = qw + 32;

    for (int kv0 = 0; kv0 < nkv; kv0 += 64) {
        // ---- S^T = K * Q^T  (two 32-kv tiles), log2 domain ----
        f32x16 s0 = {}, s1 = {};
        const u16* Kr = Kp + (long)(kv0 + lq) * 64 + hi * 8;
        __builtin_amdgcn_s_setprio(1);
#pragma unroll
        for (int ks = 0; ks < 4; ++ks)
            s0 = __builtin_amdgcn_mfma_f32_32x32x16_bf16(
                ld16(Kr + ks * 16), qf[ks], s0, 0, 0, 0);
        const u16* Kr2 = Kr + 32 * 64;
#pragma unroll
        for (int ks = 0; ks < 4; ++ks)
            s1 = __builtin_amdgcn_mfma_f32_32x32x16_bf16(
                ld16(Kr2 + ks * 16), qf[ks], s1, 0, 0, 0);
        __builtin_amdgcn_s_setprio(0);

        // ---- V prefetch (latency hides under softmax below) ----
        const u16* Vr = Vp + (long)lq * 2048 + kv0 + hi * 8;
        short8 vf0[4], vf1[4];
#pragma unroll
        for (int c = 0; c < 4; ++c) {
            vf0[c] = ld16(Vr + c * 16);
            vf1[c] = ld16(Vr + 32 * 2048 + c * 16);
        }

        // ---- causal mask (diagonal tile only) + row max ----
        float mt = -1e30f;
        if (kv0 + 64 >= nkv) {               // diagonal tile
#pragma unroll
            for (int r = 0; r < 16; ++r) {
                const int kv = kv0 + (r & 3) + 8 * (r >> 2) + 4 * hi;
                if (kv > q_abs) s0[r] = -1e30f;
                mt = fmaxf(mt, s0[r]);
                if (kv + 32 > q_abs) s1[r] = -1e30f;
                mt = fmaxf(mt, s1[r]);
            }
        } else {
#pragma unroll
            for (int r = 0; r < 16; ++r)
                mt = fmaxf(mt, fmaxf(s0[r], s1[r]));
        }
        mt = fmaxf(mt, __shfl_xor(mt, 32));

        // ---- defer-max: rescale only when max grew past threshold ----
        if (!__all(mt <= m + 11.5f)) {
            const float mn = fmaxf(m, mt);
            const float corr = __builtin_amdgcn_exp2f(m - mn);
            m = mn;
            l *= corr;
            o0 *= corr; o1 *= corr;
        }
        float ps = 0.f;
#pragma unroll
        for (int r = 0; r < 16; ++r) {
            s0[r] = __builtin_amdgcn_exp2f(s0[r] - m); ps += s0[r];
            s1[r] = __builtin_amdgcn_exp2f(s1[r] - m); ps += s1[r];
        }
        l += ps;

        // ---- build P^T B-frags (4 chunks of kv16), 2 shuffles each ----
        short8 pf[4];
#pragma unroll
        for (int c = 0; c < 4; ++c) {
            const f32x16& src = (c >> 1) ? s1 : s0;
            const int b = (c & 1) * 8;
            const unsigned A0 = pk2(src[b + 0], src[b + 1]);
            const unsigned A1 = pk2(src[b + 2], src[b + 3]);
            const unsigned B0 = pk2(src[b + 4], src[b + 5]);
            const unsigned B1 = pk2(src[b + 6], src[b + 7]);
            const unsigned S0 = hi ? A0 : B0;
            const unsigned S1 = hi ? A1 : B1;
            const unsigned R0 = (unsigned)__shfl_xor((int)S0, 32);
            const unsigned R1 = (unsigned)__shfl_xor((int)S1, 32);
            union { unsigned u[4]; short8 v; } fr;
            fr.u[0] = hi ? R0 : A0;
            fr.u[1] = hi ? R1 : A1;
            fr.u[2] = hi ? B0 : R0;
            fr.u[3] = hi ? B1 : R1;
            pf[c] = fr.v;
        }

        // ---- O^T += Vt * P^T ----
        __builtin_amdgcn_s_setprio(1);
#pragma unroll
        for (int c = 0; c < 4; ++c) {
            o0 = __builtin_amdgcn_mfma_f32_32x32x16_bf16(
                vf0[c], pf[c], o0, 0, 0, 0);
            o1 = __builtin_amdgcn_mfma_f32_32x32x16_bf16(
                vf1[c], pf[c], o1, 0, 0, 0);
        }
        __builtin_amdgcn_s_setprio(0);
    }

    // ---- finish: combine l across lane pair, normalize, store ----
    l += __shfl_xor(l, 32);
    const float inv = 1.f / l;
    u16* Orow = O + ((long)(bb * 2048 + qw + lq)) * 1024 + h * 64;
#pragma unroll
    for (int k4 = 0; k4 < 4; ++k4) {
        u16x4 w0, w1;
#pragma unroll
        for (int j = 0; j < 4; ++j) {
            w0[j] = f2bf(o0[k4 * 4 + j] * inv);
            w1[j] = f2bf(o1[k4 * 4 + j] * inv);
        }
        *reinterpret_cast<u16x4*>(Orow + 8 * k4 + 4 * hi)      = w0;
        *reinterpret_cast<u16x4*>(Orow + 32 + 8 * k4 + 4 * hi) = w1;
    }
}

// ---------------------------------------------------------------------------
// launch
// ---------------------------------------------------------------------------
extern "C" void kernel_launch(void* const* d_in, const int* in_sizes, int n_in,
                              void* d_out, int out_size, void* d_ws, size_t ws_size,
                              hipStream_t stream) {
    const float* x      = (const float*)d_in[0];
    const float* ln1_g  = (const float*)d_in[1];
    const float* ln1_b  = (const float*)d_in[2];
    const float* qkv_w  = (const float*)d_in[3];
    const float* qkv_b  = (const float*)d_in[4];
    const float* out_w  = (const float*)d_in[5];
    const float* out_b  = (const float*)d_in[6];
    const float* ln2_g  = (const float*)d_in[7];
    const float* ln2_b  = (const float*)d_in[8];
    const float* fc1_w  = (const float*)d_in[9];
    const float* fc1_b  = (const float*)d_in[10];
    const float* fc2_w  = (const float*)d_in[11];
    const float* fc2_b  = (const float*)d_in[12];
    float* out = (float*)d_out;

    const size_t MB = 1024ull * 1024ull;
    if (ws_size < 120 * MB) return;
    char* ws = (char*)d_ws;
    u16* wqkv = (u16*)(ws + 0);        // 6 MB
    u16* wout = (u16*)(ws + 6 * MB);   // 2 MB
    u16* wfc1 = (u16*)(ws + 8 * MB);   // 8 MB
    u16* wfc2 = (u16*)(ws + 16 * MB);  // 8 MB
    u16* hbuf = (u16*)(ws + 24 * MB);  // 16 MB  (LN output, bf16)
    u16* obuf = (u16*)(ws + 40 * MB);  // 16 MB  (attn output, bf16)
    u16* Qb   = (u16*)(ws + 56 * MB);  // 16 MB
    u16* Kb   = (u16*)(ws + 72 * MB);  // 16 MB
    u16* Vtb  = (u16*)(ws + 88 * MB);  // 16 MB
    u16* gbuf = (u16*)(ws + 56 * MB);  // 64 MB  (FFN hidden, reuses Q/K/Vt)

    cvt_f32_bf16<<<3072, 256, 0, stream>>>(qkv_w, wqkv, 3072 * 1024 / 4);
    cvt_f32_bf16<<<1024, 256, 0, stream>>>(out_w, wout, 1024 * 1024 / 4);
    cvt_f32_bf16<<<4096, 256, 0, stream>>>(fc1_w, wfc1, 4096 * 1024 / 4);
    cvt_f32_bf16<<<4096, 256, 0, stream>>>(fc2_w, wfc2, 1024 * 4096 / 4);

    ln_bf16<<<8192, 256, 0, stream>>>(x, ln1_g, ln1_b, hbuf);
    // QKV: 64 x 24 = 1536 blocks
    gemm_bt<3><<<dim3(1536), 256, 0, stream>>>(hbuf, wqkv, qkv_b, nullptr,
                                               nullptr, nullptr, Qb, Kb, Vtb,
                                               8192, 3072, 1024);
    attn_fwd32<<<dim3(1024), 256, 0, stream>>>(Qb, Kb, Vtb, obuf);
    // out-proj: 64 x 8 = 512 blocks
    gemm_bt<2><<<dim3(512), 256, 0, stream>>>(obuf, wout, out_b, x, out,
                                              nullptr, nullptr, nullptr, nullptr,
                                              8192, 1024, 1024);
    ln_bf16<<<8192, 256, 0, stream>>>(out, ln2_g, ln2_b, hbuf);
    // FC1: 64 x 32 = 2048 blocks
    gemm_bt<1><<<dim3(2048), 256, 0, stream>>>(hbuf, wfc1, fc1_b, nullptr,
                                               nullptr, gbuf, nullptr, nullptr,
                                               nullptr, 8192, 4096, 1024);
    // FC2: 64 x 8 = 512 blocks
    gemm_bt<2><<<dim3(512), 256, 0, stream>>>(gbuf, wfc2, fc2_b, out, out,
                                              nullptr, nullptr, nullptr, nullptr,
                                              8192, 1024, 4096);
}

// Round 9
// 404.621 us; speedup vs baseline: 1.4407x; 1.1017x over previous
//
#include <hip/hip_runtime.h>
#include <math.h>

// ---------------------------------------------------------------------------
// Types / helpers
// ---------------------------------------------------------------------------
using u16 = unsigned short;
typedef __attribute__((ext_vector_type(8))) short short8;   // 8 x bf16 (raw bits)
typedef __attribute__((ext_vector_type(4))) float f32x4;
typedef __attribute__((ext_vector_type(16))) float f32x16;
typedef __attribute__((ext_vector_type(4))) u16 u16x4;

#define DEV __device__ __forceinline__

DEV u16 f2bf(float f) {                       // f32 -> bf16, round-nearest-even
    unsigned u = __float_as_uint(f);
    u += 0x7fffu + ((u >> 16) & 1u);
    return (u16)(u >> 16);
}
DEV float bf2f(u16 h) { return __uint_as_float(((unsigned)h) << 16); }

DEV short8 ld16(const u16* p) { return *reinterpret_cast<const short8*>(p); }

DEV float gelu_f(float x) { return 0.5f * x * (1.f + erff(x * 0.70710678118654752f)); }

DEV unsigned pk2(float a, float b) {          // packed bf16x2 via HW cvt (RNE)
    unsigned r;
    asm("v_cvt_pk_bf16_f32 %0, %1, %2" : "=v"(r) : "v"(a), "v"(b));
    return r;
}

// async global->LDS, 16B per lane, LDS dest = wave-uniform base + lane*16
#define GLL16(gp, lp)                                                          \
    __builtin_amdgcn_global_load_lds(                                          \
        (const __attribute__((address_space(1))) void*)(gp),                   \
        (__attribute__((address_space(3))) void*)(lp), 16, 0, 0)

#define VMC(n) asm volatile("s_waitcnt vmcnt(" #n ")" ::: "memory")
#define LGKM0() asm volatile("s_waitcnt lgkmcnt(0)" ::: "memory")

// ---------------------------------------------------------------------------
// fp32 -> bf16 convert (weights)
// ---------------------------------------------------------------------------
__global__ void cvt_f32_bf16(const float* __restrict__ in, u16* __restrict__ out, int n4) {
    int i = blockIdx.x * 256 + threadIdx.x;
    if (i >= n4) return;
    float4 v = reinterpret_cast<const float4*>(in)[i];
    u16x4 o;
    o.x = f2bf(v.x); o.y = f2bf(v.y); o.z = f2bf(v.z); o.w = f2bf(v.w);
    reinterpret_cast<u16x4*>(out)[i] = o;
}

// ---------------------------------------------------------------------------
// LayerNorm (fp32 in) -> bf16 out.  One block per row, 256 threads x 4 floats.
// ---------------------------------------------------------------------------
__global__ __launch_bounds__(256) void ln_bf16(const float* __restrict__ x,
                                               const float* __restrict__ gm,
                                               const float* __restrict__ bt,
                                               u16* __restrict__ out) {
    const int row = blockIdx.x, tid = threadIdx.x;
    const float4 v = reinterpret_cast<const float4*>(x + (long)row * 1024)[tid];
    float s  = v.x + v.y + v.z + v.w;
    float sq = v.x * v.x + v.y * v.y + v.z * v.z + v.w * v.w;
#pragma unroll
    for (int off = 1; off <= 32; off <<= 1) {
        s  += __shfl_xor(s, off);
        sq += __shfl_xor(sq, off);
    }
    __shared__ float ss[4], ssq[4];
    const int wave = tid >> 6, lane = tid & 63;
    if (lane == 0) { ss[wave] = s; ssq[wave] = sq; }
    __syncthreads();
    s  = ss[0] + ss[1] + ss[2] + ss[3];
    sq = ssq[0] + ssq[1] + ssq[2] + ssq[3];
    const float mu   = s * (1.f / 1024.f);
    const float var  = sq * (1.f / 1024.f) - mu * mu;
    const float rstd = rsqrtf(var + 1e-5f);
    const float4 g4 = reinterpret_cast<const float4*>(gm)[tid];
    const float4 b4 = reinterpret_cast<const float4*>(bt)[tid];
    u16x4 o;
    o.x = f2bf((v.x - mu) * rstd * g4.x + b4.x);
    o.y = f2bf((v.y - mu) * rstd * g4.y + b4.y);
    o.z = f2bf((v.z - mu) * rstd * g4.z + b4.z);
    o.w = f2bf((v.w - mu) * rstd * g4.w + b4.w);
    reinterpret_cast<u16x4*>(out + (long)row * 1024)[tid] = o;
}

// ---------------------------------------------------------------------------
// m97-style GEMM + counted-vmcnt 3-deep pipeline: C = A @ B^T + bias.
// 128x128 tile, BK=32, 4 waves (2x2), 3 LDS buffers (48 KB).  Tile t staged
// at t-3; per iter: VMC(8)->bar; ds_read; lgkm0; bar; STAGE(t+3); MFMA.
// XOR-swizzled LDS (pre-swizzled source + swizzled ds_read; 0 conflicts).
// MFMA (bfr, af) order -> row-major D frag -> vectorized epilogue stores.
// EPI: 0 = bf16 out, 1 = bf16 gelu out, 2 = fp32 out + residual,
//      3 = QKV: Q (pre-scaled by 1/sqrt(64)*log2e) / K direct; V via
//          in-LDS 128x128 transpose -> Vt (reuses the staging pool).
// ---------------------------------------------------------------------------
#define TS(c, r) ((c) * 128 + (((((r) >> 3) ^ ((c) & 15))) << 3) + ((r) & 7))

template <int EPI>
__global__ __launch_bounds__(256, 3) void gemm_bt(
    const u16* __restrict__ A, const u16* __restrict__ B,
    const float* __restrict__ bias, const float* res, float* outf,
    u16* __restrict__ outb, u16* __restrict__ Qb, u16* __restrict__ Kb,
    u16* __restrict__ Vtb, int M, int N, int K) {
    __shared__ u16 shpool[24576];   // 3 bufs x (A 8KB + B 8KB); also Vt transpose

    const int tid = threadIdx.x;
    const int wave = tid >> 6, lane = tid & 63;
    const int lo = lane & 15, g = lane >> 4;
    const int wr = wave >> 1, wc = wave & 1;

    // XCD-chunked bijective swizzle; bn fastest (co-resident blocks share A)
    const int nwg = gridDim.x, chunk = nwg >> 3;
    const int wgid = (blockIdx.x & 7) * chunk + (blockIdx.x >> 3);
    const int NB = N >> 7;
    const int bm = wgid / NB, bn = wgid % NB;
    const int row0 = bm * 128, col0 = bn * 128;

    // staging source (pre-swizzled logical chunk so linear LDS dest = swizzled)
    const int lrow = lane >> 2;
    const int lg   = (lane & 3) ^ ((lane >> 3) & 3);
    const u16* Ag = A + (long)(row0 + wave * 16 + lrow) * K + lg * 8;
    const u16* Bg = B + (long)(col0 + wave * 16 + lrow) * K + lg * 8;

#define STAGE(tb, kt) do {                                                     \
        u16* Al = shpool + (tb) * 8192 + wave * 512;                           \
        u16* Bl = Al + 4096;                                                   \
        GLL16(Ag + (long)(kt) * 32, Al);                                       \
        GLL16(Ag + 64 * (long)K + (long)(kt) * 32, Al + 2048);                 \
        GLL16(Bg + (long)(kt) * 32, Bl);                                       \
        GLL16(Bg + 64 * (long)K + (long)(kt) * 32, Bl + 2048);                 \
    } while (0)

    const int agp = g ^ ((lo >> 1) & 3);      // swizzled ds_read chunk
    f32x4 acc[4][4] = {};

    STAGE(0, 0);
    STAGE(1, 1);
    STAGE(2, 2);

    const int T = K >> 5;
    int cur = 0;
    for (int t = 0; t < T; ++t) {
        if (t + 2 < T) { VMC(8); }
        else if (t + 1 < T) { VMC(4); }
        else { VMC(0); }
        __builtin_amdgcn_s_barrier();         // tile t visible to all waves
        const u16* As = shpool + cur * 8192;
        const u16* Bs = As + 4096;
        short8 af[4], bfr[4];
#pragma unroll
        for (int m = 0; m < 4; ++m)
            af[m] = ld16(&As[(wr * 64 + m * 16 + lo) * 32 + agp * 8]);
#pragma unroll
        for (int n = 0; n < 4; ++n)
            bfr[n] = ld16(&Bs[(wc * 64 + n * 16 + lo) * 32 + agp * 8]);
        LGKM0();                              // own reads drained (WAR fence)
        __builtin_amdgcn_s_barrier();         // all waves' reads done
        if (t + 3 < T) STAGE(cur, t + 3);     // safe overwrite; flies under MFMA
#pragma unroll
        for (int m = 0; m < 4; ++m)
#pragma unroll
            for (int n = 0; n < 4; ++n)
                acc[m][n] = __builtin_amdgcn_mfma_f32_16x16x32_bf16(
                    bfr[n], af[m], acc[m][n], 0, 0, 0);
        cur = (cur == 2) ? 0 : cur + 1;
    }
#undef STAGE

    // ---- epilogue: row-major frags: row = ...+lo, 4 consecutive cols ----
    if constexpr (EPI == 3) {
        if (col0 >= 2048) {       // V block: transpose via LDS, coalesced Vt
            __syncthreads();      // all waves out of the K-loop (LDS reuse)
#pragma unroll
            for (int n = 0; n < 4; ++n) {
                const int cb = wc * 64 + n * 16 + g * 4;
                const float4 b4 = *reinterpret_cast<const float4*>(&bias[col0 + cb]);
#pragma unroll
                for (int m = 0; m < 4; ++m) {
                    const int rl = wr * 64 + m * 16 + lo;
                    shpool[TS(cb + 0, rl)] = f2bf(acc[m][n][0] + b4.x);
                    shpool[TS(cb + 1, rl)] = f2bf(acc[m][n][1] + b4.y);
                    shpool[TS(cb + 2, rl)] = f2bf(acc[m][n][2] + b4.z);
                    shpool[TS(cb + 3, rl)] = f2bf(acc[m][n][3] + b4.w);
                }
            }
            __syncthreads();
            const int c = tid >> 1, half = tid & 1;
            const int dcol = (col0 - 2048) + c;
            const int head = dcol >> 6, d = dcol & 63;
            const int bb = row0 >> 11;
            u16* dst = Vtb + ((long)(bb * 16 + head) * 64 + d) * 2048 +
                       (row0 & 2047) + half * 64;
            const u16* srcb = shpool + c * 128;
#pragma unroll
            for (int i = 0; i < 8; ++i) {
                const int pc = (half * 8 + i) ^ (c & 15);
                *reinterpret_cast<short8*>(dst + i * 8) =
                    *reinterpret_cast<const short8*>(srcb + pc * 8);
            }
            return;
        }
    }
#pragma unroll
    for (int n = 0; n < 4; ++n) {
        const int cb = col0 + wc * 64 + n * 16 + g * 4;
        const float4 b4 = *reinterpret_cast<const float4*>(&bias[cb]);
#pragma unroll
        for (int m = 0; m < 4; ++m) {
            const int r = row0 + wr * 64 + m * 16 + lo;
            const float v0 = acc[m][n][0] + b4.x;
            const float v1 = acc[m][n][1] + b4.y;
            const float v2 = acc[m][n][2] + b4.z;
            const float v3 = acc[m][n][3] + b4.w;
            if constexpr (EPI == 0) {
                u16x4 o = {f2bf(v0), f2bf(v1), f2bf(v2), f2bf(v3)};
                *reinterpret_cast<u16x4*>(&outb[(long)r * N + cb]) = o;
            } else if constexpr (EPI == 1) {
                u16x4 o = {f2bf(gelu_f(v0)), f2bf(gelu_f(v1)),
                           f2bf(gelu_f(v2)), f2bf(gelu_f(v3))};
                *reinterpret_cast<u16x4*>(&outb[(long)r * N + cb]) = o;
            } else if constexpr (EPI == 2) {
                const float4 rr = *reinterpret_cast<const float4*>(&res[(long)r * N + cb]);
                float4 o = {rr.x + v0, rr.y + v1, rr.z + v2, rr.w + v3};
                *reinterpret_cast<float4*>(&outf[(long)r * N + cb]) = o;
            } else {  // EPI == 3, Q/K block
                const int part = cb >> 10, cc = cb & 1023;
                const int head = cc >> 6, d = cc & 63;
                const int bb = r >> 11, srow = r & 2047;
                const int bh = bb * 16 + head;
                // Q pre-scaled into log2 domain for exp2 softmax
                const float qs = (part == 0) ? 0.18033688f : 1.0f;
                u16x4 o = {f2bf(v0 * qs), f2bf(v1 * qs), f2bf(v2 * qs), f2bf(v3 * qs)};
                u16* base = (part == 0) ? Qb : Kb;
                *reinterpret_cast<u16x4*>(&base[((long)bh * 2048 + srow) * 64 + d]) = o;
            }
        }
    }
}

// ---------------------------------------------------------------------------
// Causal flash attention, 32x32x16 MFMA, LDS-staged K/V (counted-vmcnt
// double-buffer).  Block = 4 waves = one (bh, 128-row q-strip); per 64-kv
// tile, K[64x64] and Vt[64x64] staged into LDS with the G4 XOR swizzle
// (byte ^= (row&7)<<4, applied via pre-swizzled global source).  Waves past
// their causal end skip compute but keep staging + barriers (uniform sync).
// exp2-domain softmax (Q pre-scaled); defer-max; setprio on MFMA.
// ---------------------------------------------------------------------------
__global__ __launch_bounds__(256) void attn_fwd32(
    const u16* __restrict__ Q, const u16* __restrict__ K,
    const u16* __restrict__ Vt, u16* __restrict__ O) {
    __shared__ u16 kvl[2][8192];   // per buf: K tile 4096 u16, V tile 4096 u16
    const int bh = blockIdx.x;
    const int strip = 15 - blockIdx.y;       // heavy strips dispatch first
    const int wave = threadIdx.x >> 6, lane = threadIdx.x & 63;
    const int lq = lane & 31, hi = lane >> 5;
    const int qw = strip * 128 + wave * 32;

    const u16* Kg = K + (long)bh * 2048 * 64;
    const u16* Vg = Vt + (long)bh * 64 * 2048;
    const int bb = bh >> 4, h = bh & 15;
    const u16* Qp = Q + ((long)bh * 2048 + qw) * 64;

    // staging thread map: call covers 32 rows x 8 chunks; pre-swizzled source
    const int srow = wave * 8 + (lane >> 3);         // 0..31
    const int sc   = (lane & 7) ^ (srow & 7);        // logical 16B chunk

#define ASTAGE(b, kt) do {                                                     \
        const long kvb = (long)(kt) * 64;                                      \
        GLL16(Kg + (kvb + srow) * 64 + sc * 8,        &kvl[b][wave * 512]);    \
        GLL16(Kg + (kvb + 32 + srow) * 64 + sc * 8,   &kvl[b][2048 + wave * 512]); \
        GLL16(Vg + (long)srow * 2048 + kvb + sc * 8,  &kvl[b][4096 + wave * 512]); \
        GLL16(Vg + (long)(32 + srow) * 2048 + kvb + sc * 8,                    \
              &kvl[b][6144 + wave * 512]);                                     \
    } while (0)

    short8 qf[4];
#pragma unroll
    for (int ks = 0; ks < 4; ++ks)
        qf[ks] = ld16(Qp + lq * 64 + ks * 16 + hi * 8);

    f32x16 o0 = {}, o1 = {};
    float m = -1e30f, l = 0.f;
    const int q_abs = qw + lq;
    const int my_end = qw + 32;              // wave's causal kv end
    const int T = 2 * (strip + 1);           // block kv tiles (>= 2)
    const int swp = lq & 7;                  // read-side swizzle key

    ASTAGE(0, 0);
    ASTAGE(1, 1);

    for (int t = 0; t < T; ++t) {
        const int cur = t & 1;
        const int kv0 = t * 64;
        if (t + 1 < T) { VMC(4); } else { VMC(0); }
        __builtin_amdgcn_s_barrier();        // tile t landed for all waves
        const bool active = (kv0 < my_end);  // wave-uniform
        f32x16 s0 = {}, s1 = {};
        short8 vf0[4], vf1[4];
        if (active) {
            const u16* Kb = &kvl[cur][0];
            __builtin_amdgcn_s_setprio(1);
#pragma unroll
            for (int ks = 0; ks < 4; ++ks)
                s0 = __builtin_amdgcn_mfma_f32_32x32x16_bf16(
                    ld16(Kb + lq * 64 + ((ks * 2 + hi) ^ swp) * 8), qf[ks], s0, 0, 0, 0);
#pragma unroll
            for (int ks = 0; ks < 4; ++ks)
                s1 = __builtin_amdgcn_mfma_f32_32x32x16_bf16(
                    ld16(Kb + 2048 + lq * 64 + ((ks * 2 + hi) ^ swp) * 8), qf[ks], s1, 0, 0, 0);
            __builtin_amdgcn_s_setprio(0);
            const u16* Vb = &kvl[cur][4096];
#pragma unroll
            for (int c = 0; c < 4; ++c) {
                vf0[c] = ld16(Vb + lq * 64 + ((c * 2 + hi) ^ swp) * 8);
                vf1[c] = ld16(Vb + 2048 + lq * 64 + ((c * 2 + hi) ^ swp) * 8);
            }
        }
        LGKM0();                             // own LDS reads drained (WAR)
        __builtin_amdgcn_s_barrier();        // all waves' reads done
        if (t + 2 < T) ASTAGE(cur, t + 2);   // overwrite safe; flies under compute
        if (active) {
            // ---- causal mask (diagonal tiles) + row max ----
            float mt = -1e30f;
            if (kv0 + 64 >= my_end) {
#pragma unroll
                for (int r = 0; r < 16; ++r) {
                    const int kv = kv0 + (r & 3) + 8 * (r >> 2) + 4 * hi;
                    if (kv > q_abs) s0[r] = -1e30f;
                    mt = fmaxf(mt, s0[r]);
                    if (kv + 32 > q_abs) s1[r] = -1e30f;
                    mt = fmaxf(mt, s1[r]);
                }
            } else {
#pragma unroll
                for (int r = 0; r < 16; ++r)
                    mt = fmaxf(mt, fmaxf(s0[r], s1[r]));
            }
            mt = fmaxf(mt, __shfl_xor(mt, 32));

            // ---- defer-max rescale ----
            if (!__all(mt <= m + 11.5f)) {
                const float mn = fmaxf(m, mt);
                const float corr = __builtin_amdgcn_exp2f(m - mn);
                m = mn;
                l *= corr;
                o0 *= corr; o1 *= corr;
            }
            float ps = 0.f;
#pragma unroll
            for (int r = 0; r < 16; ++r) {
                s0[r] = __builtin_amdgcn_exp2f(s0[r] - m); ps += s0[r];
                s1[r] = __builtin_amdgcn_exp2f(s1[r] - m); ps += s1[r];
            }
            l += ps;

            // ---- build P^T B-frags (4 chunks of kv16) ----
            short8 pf[4];
#pragma unroll
            for (int c = 0; c < 4; ++c) {
                const f32x16& src = (c >> 1) ? s1 : s0;
                const int b = (c & 1) * 8;
                const unsigned A0 = pk2(src[b + 0], src[b + 1]);
                const unsigned A1 = pk2(src[b + 2], src[b + 3]);
                const unsigned B0 = pk2(src[b + 4], src[b + 5]);
                const unsigned B1 = pk2(src[b + 6], src[b + 7]);
                const unsigned S0 = hi ? A0 : B0;
                const unsigned S1 = hi ? A1 : B1;
                const unsigned R0 = (unsigned)__shfl_xor((int)S0, 32);
                const unsigned R1 = (unsigned)__shfl_xor((int)S1, 32);
                union { unsigned u[4]; short8 v; } fr;
                fr.u[0] = hi ? R0 : A0;
                fr.u[1] = hi ? R1 : A1;
                fr.u[2] = hi ? B0 : R0;
                fr.u[3] = hi ? B1 : R1;
                pf[c] = fr.v;
            }

            // ---- O^T += Vt * P^T ----
            __builtin_amdgcn_s_setprio(1);
#pragma unroll
            for (int c = 0; c < 4; ++c) {
                o0 = __builtin_amdgcn_mfma_f32_32x32x16_bf16(
                    vf0[c], pf[c], o0, 0, 0, 0);
                o1 = __builtin_amdgcn_mfma_f32_32x32x16_bf16(
                    vf1[c], pf[c], o1, 0, 0, 0);
            }
            __builtin_amdgcn_s_setprio(0);
        }
    }
#undef ASTAGE

    // ---- finish: combine l across lane pair, normalize, store ----
    l += __shfl_xor(l, 32);
    const float inv = 1.f / l;
    u16* Orow = O + ((long)(bb * 2048 + qw + lq)) * 1024 + h * 64;
#pragma unroll
    for (int k4 = 0; k4 < 4; ++k4) {
        u16x4 w0, w1;
#pragma unroll
        for (int j = 0; j < 4; ++j) {
            w0[j] = f2bf(o0[k4 * 4 + j] * inv);
            w1[j] = f2bf(o1[k4 * 4 + j] * inv);
        }
        *reinterpret_cast<u16x4*>(Orow + 8 * k4 + 4 * hi)      = w0;
        *reinterpret_cast<u16x4*>(Orow + 32 + 8 * k4 + 4 * hi) = w1;
    }
}

// ---------------------------------------------------------------------------
// launch
// ---------------------------------------------------------------------------
extern "C" void kernel_launch(void* const* d_in, const int* in_sizes, int n_in,
                              void* d_out, int out_size, void* d_ws, size_t ws_size,
                              hipStream_t stream) {
    const float* x      = (const float*)d_in[0];
    const float* ln1_g  = (const float*)d_in[1];
    const float* ln1_b  = (const float*)d_in[2];
    const float* qkv_w  = (const float*)d_in[3];
    const float* qkv_b  = (const float*)d_in[4];
    const float* out_w  = (const float*)d_in[5];
    const float* out_b  = (const float*)d_in[6];
    const float* ln2_g  = (const float*)d_in[7];
    const float* ln2_b  = (const float*)d_in[8];
    const float* fc1_w  = (const float*)d_in[9];
    const float* fc1_b  = (const float*)d_in[10];
    const float* fc2_w  = (const float*)d_in[11];
    const float* fc2_b  = (const float*)d_in[12];
    float* out = (float*)d_out;

    const size_t MB = 1024ull * 1024ull;
    if (ws_size < 120 * MB) return;
    char* ws = (char*)d_ws;
    u16* wqkv = (u16*)(ws + 0);        // 6 MB
    u16* wout = (u16*)(ws + 6 * MB);   // 2 MB
    u16* wfc1 = (u16*)(ws + 8 * MB);   // 8 MB
    u16* wfc2 = (u16*)(ws + 16 * MB);  // 8 MB
    u16* hbuf = (u16*)(ws + 24 * MB);  // 16 MB  (LN output, bf16)
    u16* obuf = (u16*)(ws + 40 * MB);  // 16 MB  (attn output, bf16)
    u16* Qb   = (u16*)(ws + 56 * MB);  // 16 MB
    u16* Kb   = (u16*)(ws + 72 * MB);  // 16 MB
    u16* Vtb  = (u16*)(ws + 88 * MB);  // 16 MB
    u16* gbuf = (u16*)(ws + 56 * MB);  // 64 MB  (FFN hidden, reuses Q/K/Vt)

    cvt_f32_bf16<<<3072, 256, 0, stream>>>(qkv_w, wqkv, 3072 * 1024 / 4);
    cvt_f32_bf16<<<1024, 256, 0, stream>>>(out_w, wout, 1024 * 1024 / 4);
    cvt_f32_bf16<<<4096, 256, 0, stream>>>(fc1_w, wfc1, 4096 * 1024 / 4);
    cvt_f32_bf16<<<4096, 256, 0, stream>>>(fc2_w, wfc2, 1024 * 4096 / 4);

    ln_bf16<<<8192, 256, 0, stream>>>(x, ln1_g, ln1_b, hbuf);
    // QKV: 64 x 24 = 1536 blocks
    gemm_bt<3><<<dim3(1536), 256, 0, stream>>>(hbuf, wqkv, qkv_b, nullptr,
                                               nullptr, nullptr, Qb, Kb, Vtb,
                                               8192, 3072, 1024);
    attn_fwd32<<<dim3(64, 16), 256, 0, stream>>>(Qb, Kb, Vtb, obuf);
    // out-proj: 64 x 8 = 512 blocks
    gemm_bt<2><<<dim3(512), 256, 0, stream>>>(obuf, wout, out_b, x, out,
                                              nullptr, nullptr, nullptr, nullptr,
                                              8192, 1024, 1024);
    ln_bf16<<<8192, 256, 0, stream>>>(out, ln2_g, ln2_b, hbuf);
    // FC1: 64 x 32 = 2048 blocks
    gemm_bt<1><<<dim3(2048), 256, 0, stream>>>(hbuf, wfc1, fc1_b, nullptr,
                                               nullptr, gbuf, nullptr, nullptr,
                                               nullptr, 8192, 4096, 1024);
    // FC2: 64 x 8 = 512 blocks
    gemm_bt<2><<<dim3(512), 256, 0, stream>>>(gbuf, wfc2, fc2_b, out, out,
                                              nullptr, nullptr, nullptr, nullptr,
                                              8192, 1024, 4096);
}